// Round 2
// baseline (828.020 us; speedup 1.0000x reference)
//
#include <hip/hip_runtime.h>
#include <hip/hip_bf16.h>

// RGCN: N=4096, D=128, R=8, B=8, two layers + LN(+ReLU).
// R2: pre-packed bf16 adjacency + nibble edge-types, 4 blocks/CU agg,
// XCD-swizzled grid. Register-level relation masking feeding bf16 MFMA.

#define NN 4096
#define DD 128

typedef __attribute__((ext_vector_type(8))) short  s16x8;   // storage for 8 bf16
typedef __attribute__((ext_vector_type(8))) __bf16 bf16v8;  // MFMA operand type
typedef __attribute__((ext_vector_type(4))) float  f32x4;
typedef __attribute__((ext_vector_type(4))) int    i32x4;

__device__ inline short f2bf(float f) {            // f32 -> bf16 bits, RNE
  union { float f; unsigned u; } v; v.f = f;
  unsigned r = (v.u + 0x7FFFu + ((v.u >> 16) & 1u)) >> 16;
  return (short)r;
}

__device__ inline f32x4 mfma16(s16x8 a, s16x8 b, f32x4 c) {
  return __builtin_amdgcn_mfma_f32_16x16x32_bf16(
      __builtin_bit_cast(bf16v8, a), __builtin_bit_cast(bf16v8, b), c, 0, 0, 0);
}

// ---------------------------------------------------------------------------
// K0: pack adj (f32 -> bf16) and edge_type (i32 -> 4-bit nibbles, 8 per u32).
// One thread per 8 consecutive elements of a row. Grid 8192 x 256.
// ---------------------------------------------------------------------------
__global__ void pack_kernel(const float* __restrict__ adj, const int* __restrict__ et,
                            short* __restrict__ adjb, unsigned* __restrict__ etp) {
  int g = blockIdx.x * 256 + threadIdx.x;     // 0 .. 2M-1
  size_t base = (size_t)g * 8;
  f32x4 f0 = *(const f32x4*)(adj + base);
  f32x4 f1 = *(const f32x4*)(adj + base + 4);
  i32x4 e0 = *(const i32x4*)(et + base);
  i32x4 e1 = *(const i32x4*)(et + base + 4);
  short v[8];
#pragma unroll
  for (int e = 0; e < 4; ++e) v[e] = f2bf(f0[e]);
#pragma unroll
  for (int e = 0; e < 4; ++e) v[4 + e] = f2bf(f1[e]);
  unsigned pk = 0;
#pragma unroll
  for (int e = 0; e < 4; ++e) pk |= ((unsigned)e0[e] & 7u) << (4 * e);
#pragma unroll
  for (int e = 0; e < 4; ++e) pk |= ((unsigned)e1[e] & 7u) << (4 * (e + 4));
  *(s16x8*)(adjb + base) = *(s16x8*)v;
  etp[g] = pk;
}

// ---------------------------------------------------------------------------
// K1: w_r = sum_b weights[r,b]*bases[b]  (plus r==8 -> W_self), written
// pre-fragmented as B-operand frags: [layer][r(9)][s(4 k-steps)][t(8 o-tiles)]
// [lane(64)][e(8)], element = w[i = 32s+8*(l>>4)+e][o = 16t+(l&15)].
// ---------------------------------------------------------------------------
__global__ void prep_w(const float* __restrict__ b1, const float* __restrict__ w1,
                       const float* __restrict__ ws1,
                       const float* __restrict__ b2, const float* __restrict__ w2,
                       const float* __restrict__ ws2,
                       short* __restrict__ wfrag) {
  int tid = blockIdx.x * 256 + threadIdx.x;   // 0..36863 (2 layers x 18432)
  int layer = (tid >= 18432);
  int t0 = tid - layer * 18432;
  int lane = t0 & 63;
  int t = (t0 >> 6) & 7;
  int s = (t0 >> 9) & 3;
  int r = t0 >> 11;                            // 0..8
  const float* bases = layer ? b2 : b1;
  const float* wts   = layer ? w2 : w1;
  const float* wself = layer ? ws2 : ws1;
  int o  = t * 16 + (lane & 15);
  int i0 = s * 32 + 8 * (lane >> 4);
  short v[8];
#pragma unroll
  for (int e = 0; e < 8; ++e) {
    int i = i0 + e;
    float a;
    if (r < 8) {
      a = 0.f;
#pragma unroll
      for (int b = 0; b < 8; ++b)
        a += wts[r * 8 + b] * bases[((size_t)b * 128 + i) * 128 + o];
    } else {
      a = wself[(size_t)i * 128 + o];
    }
    v[e] = f2bf(a);
  }
  *(s16x8*)(wfrag + (size_t)tid * 8) = *(s16x8*)v;
}

// ---------------------------------------------------------------------------
// K2: xw_r = xin @ w_r for r=0..7 -> xwfrag in aggregation-B-frag layout
//     [r][mstep(128)][t(8)][lane(64)][e(8)], elem = xw[r][32*ms+8*(l>>4)+e][16t+(l&15)]
//     r==8: hacc = xin @ W_self + bias   (f32, plain stores; base for atomics)
// ---------------------------------------------------------------------------
__global__ void xw_gemm(const float* __restrict__ xin, const short* __restrict__ wfrag,
                        short* __restrict__ xwfrag, float* __restrict__ hacc,
                        const float* __restrict__ bias) {
  __shared__ short lds[4][32 * 128];
  int w = threadIdx.x >> 6, lane = threadIdx.x & 63;
  int widx = blockIdx.x * 4 + w;   // 0..1151
  int m = widx & 127;              // 32-row tile
  int r = widx >> 7;               // 0..8
  int l15 = lane & 15, l4 = lane >> 4;

  f32x4 acc[2][8] = {};

#pragma unroll
  for (int s = 0; s < 4; ++s) {
    s16x8 A[2];
#pragma unroll
    for (int nt = 0; nt < 2; ++nt) {
      const float* xp = xin + (size_t)(m * 32 + nt * 16 + l15) * 128 + s * 32 + 8 * l4;
      f32x4 f0 = *(const f32x4*)xp;
      f32x4 f1 = *(const f32x4*)(xp + 4);
      s16x8 av;
#pragma unroll
      for (int e = 0; e < 4; ++e) av[e] = f2bf(f0[e]);
#pragma unroll
      for (int e = 0; e < 4; ++e) av[4 + e] = f2bf(f1[e]);
      A[nt] = av;
    }
    const short* bp = wfrag + ((size_t)(r * 4 + s) * 8) * 512 + lane * 8;
#pragma unroll
    for (int t = 0; t < 8; ++t) {
      s16x8 B = *(const s16x8*)(bp + t * 512);
      acc[0][t] = mfma16(A[0], B, acc[0][t]);
      acc[1][t] = mfma16(A[1], B, acc[1][t]);
    }
  }

  if (r == 8) {
#pragma unroll
    for (int nt = 0; nt < 2; ++nt)
#pragma unroll
      for (int t = 0; t < 8; ++t)
#pragma unroll
        for (int j = 0; j < 4; ++j) {
          int row = m * 32 + nt * 16 + 4 * l4 + j;
          int col = t * 16 + l15;
          hacc[(size_t)row * 128 + col] = acc[nt][t][j] + bias[col];
        }
  } else {
#pragma unroll
    for (int nt = 0; nt < 2; ++nt)
#pragma unroll
      for (int t = 0; t < 8; ++t)
#pragma unroll
        for (int j = 0; j < 4; ++j)
          lds[w][(nt * 16 + 4 * l4 + j) * 128 + t * 16 + l15] = f2bf(acc[nt][t][j]);
    __syncthreads();
#pragma unroll
    for (int t = 0; t < 8; ++t) {
      short v[8];
#pragma unroll
      for (int e = 0; e < 8; ++e) v[e] = lds[w][(8 * l4 + e) * 128 + t * 16 + l15];
      *(s16x8*)(xwfrag + ((size_t)(r * 128 + m) * 8 + t) * 512 + lane * 8) = *(s16x8*)v;
    }
  }
}

// ---------------------------------------------------------------------------
// K3: hacc += sum_r (adj .* (et==r)) @ xw_r
// Block = 4 waves, 128x128 output tile (wave = 64 rows x 64 cols).
// Grid = 32 rowblk x 32 kc = 1024 blocks (4/CU), XCD-swizzled.
// PACKED: A from bf16 adjb + nibble etp.  Fallback: raw f32 adj + i32 et.
// ---------------------------------------------------------------------------
template <bool PACKED>
__launch_bounds__(256, 4)
__global__ void agg_kernel(const float* __restrict__ adj, const int* __restrict__ et,
                           const short* __restrict__ adjb, const unsigned* __restrict__ etp,
                           const short* __restrict__ xwfrag, float* __restrict__ hacc) {
  int w = threadIdx.x >> 6, lane = threadIdx.x & 63;
  // XCD-aware swizzle: 1024 % 8 == 0 -> simple form is bijective.
  int wid = (blockIdx.x & 7) * 128 + (blockIdx.x >> 3);
  int rowblk = wid >> 5;              // 0..31 : 128 rows
  int kc = wid & 31;                  // 0..31 : k-chunk of 128 m
  int wr = w >> 1, wc = w & 1;
  int rowbase = rowblk * 128 + wr * 64;
  int l15 = lane & 15, l4 = lane >> 4;

  f32x4 acc[4][4] = {};

  for (int ms = 0; ms < 4; ++ms) {
    int gm = kc * 4 + ms;            // global 32-wide m-step
    s16x8 a[4]; s16x8 cd[4];
#pragma unroll
    for (int nt = 0; nt < 4; ++nt) {
      size_t row = (size_t)(rowbase + nt * 16 + l15);
      if (PACKED) {
        a[nt] = *(const s16x8*)(adjb + row * 4096 + gm * 32 + 8 * l4);
        unsigned pk = etp[row * 512 + gm * 4 + l4];
        s16x8 c;
#pragma unroll
        for (int e = 0; e < 8; ++e) c[e] = (short)((pk >> (4 * e)) & 7u);
        cd[nt] = c;
      } else {
        size_t rbase = row * 4096 + gm * 32 + 8 * l4;
        f32x4 f0 = *(const f32x4*)(adj + rbase);
        f32x4 f1 = *(const f32x4*)(adj + rbase + 4);
        i32x4 e0 = *(const i32x4*)(et + rbase);
        i32x4 e1 = *(const i32x4*)(et + rbase + 4);
        s16x8 av, c;
#pragma unroll
        for (int e = 0; e < 4; ++e) { av[e] = f2bf(f0[e]); c[e] = (short)e0[e]; }
#pragma unroll
        for (int e = 0; e < 4; ++e) { av[4 + e] = f2bf(f1[e]); c[4 + e] = (short)e1[e]; }
        a[nt] = av; cd[nt] = c;
      }
    }
#pragma unroll
    for (int r = 0; r < 8; ++r) {
      const short* bp = xwfrag + ((size_t)((r * 128 + gm) * 8 + wc * 4)) * 512 + lane * 8;
      s16x8 b[4];
#pragma unroll
      for (int t = 0; t < 4; ++t) b[t] = *(const s16x8*)(bp + t * 512);
#pragma unroll
      for (int nt = 0; nt < 4; ++nt) {
        s16x8 mfr;
#pragma unroll
        for (int e = 0; e < 8; ++e) mfr[e] = (cd[nt][e] == (short)r) ? a[nt][e] : (short)0;
#pragma unroll
        for (int t = 0; t < 4; ++t)
          acc[nt][t] = mfma16(mfr, b[t], acc[nt][t]);
      }
    }
  }

  // epilogue: k-split partials -> atomic f32 add
#pragma unroll
  for (int nt = 0; nt < 4; ++nt)
#pragma unroll
    for (int t = 0; t < 4; ++t)
#pragma unroll
      for (int j = 0; j < 4; ++j) {
        int row = rowbase + nt * 16 + 4 * l4 + j;
        int col = wc * 64 + t * 16 + l15;
        unsafeAtomicAdd(&hacc[(size_t)row * 128 + col], acc[nt][t][j]);
      }
}

// ---------------------------------------------------------------------------
// K4: row LayerNorm (+optional ReLU). One wave per row, 2 elems/lane.
// ---------------------------------------------------------------------------
__global__ void ln_kernel(const float* __restrict__ h, const float* __restrict__ gamma,
                          const float* __restrict__ beta, float* __restrict__ out,
                          int relu) {
  int row  = blockIdx.x * 4 + (threadIdx.x >> 6);
  int lane = threadIdx.x & 63;
  float2 v = *(const float2*)&h[(size_t)row * 128 + lane * 2];
  float s  = v.x + v.y;
  float sq = v.x * v.x + v.y * v.y;
#pragma unroll
  for (int off = 32; off; off >>= 1) {
    s  += __shfl_xor(s,  off);
    sq += __shfl_xor(sq, off);
  }
  float mu  = s * (1.f / 128.f);
  float var = sq * (1.f / 128.f) - mu * mu;
  float inv = rsqrtf(var + 1e-5f);
  float y0 = (v.x - mu) * inv * gamma[lane * 2]     + beta[lane * 2];
  float y1 = (v.y - mu) * inv * gamma[lane * 2 + 1] + beta[lane * 2 + 1];
  if (relu) { y0 = fmaxf(y0, 0.f); y1 = fmaxf(y1, 0.f); }
  float2 o; o.x = y0; o.y = y1;
  *(float2*)&out[(size_t)row * 128 + lane * 2] = o;
}

// ---------------------------------------------------------------------------
extern "C" void kernel_launch(void* const* d_in, const int* in_sizes, int n_in,
                              void* d_out, int out_size, void* d_ws, size_t ws_size,
                              hipStream_t stream) {
  const float* x      = (const float*)d_in[0];
  const float* adj    = (const float*)d_in[1];
  const int*   et     = (const int*)d_in[2];
  const float* bases1 = (const float*)d_in[3];
  const float* wts1   = (const float*)d_in[4];
  const float* wself1 = (const float*)d_in[5];
  const float* bself1 = (const float*)d_in[6];
  const float* bases2 = (const float*)d_in[7];
  const float* wts2   = (const float*)d_in[8];
  const float* wself2 = (const float*)d_in[9];
  const float* bself2 = (const float*)d_in[10];
  const float* gamma1 = (const float*)d_in[11];
  const float* beta1  = (const float*)d_in[12];
  const float* gamma2 = (const float*)d_in[13];
  const float* beta2  = (const float*)d_in[14];

  char* ws = (char*)d_ws;
  short*    wfrag  = (short*)(ws);                                // 589,824 B
  short*    xwfrag = (short*)(ws + 589824);                       // 8 MiB
  float*    hacc   = (float*)(ws + 589824 + 8388608);             // 2 MiB
  float*    h1     = (float*)(ws + 589824 + 8388608 + 2097152);   // 2 MiB
  short*    adjb   = (short*)(ws + 13172736);                     // 32 MiB
  unsigned* etp    = (unsigned*)(ws + 13172736 + 33554432);       // 8 MiB
  const size_t NEED_PACKED = 13172736ull + 33554432ull + 8388608ull;
  const bool packed = ws_size >= NEED_PACKED;

  prep_w<<<144, 256, 0, stream>>>(bases1, wts1, wself1, bases2, wts2, wself2, wfrag);
  if (packed)
    pack_kernel<<<8192, 256, 0, stream>>>(adj, et, adjb, etp);

  // layer 1
  xw_gemm<<<288, 256, 0, stream>>>(x, wfrag, xwfrag, hacc, bself1);
  if (packed)
    agg_kernel<true ><<<1024, 256, 0, stream>>>(adj, et, adjb, etp, xwfrag, hacc);
  else
    agg_kernel<false><<<1024, 256, 0, stream>>>(adj, et, adjb, etp, xwfrag, hacc);
  ln_kernel<<<1024, 256, 0, stream>>>(hacc, gamma1, beta1, h1, 1);

  // layer 2
  xw_gemm<<<288, 256, 0, stream>>>(h1, wfrag + 147456, xwfrag, hacc, bself2);
  if (packed)
    agg_kernel<true ><<<1024, 256, 0, stream>>>(adj, et, adjb, etp, xwfrag, hacc);
  else
    agg_kernel<false><<<1024, 256, 0, stream>>>(adj, et, adjb, etp, xwfrag, hacc);
  ln_kernel<<<1024, 256, 0, stream>>>(hacc, gamma2, beta2, (float*)d_out, 0);
}

// Round 3
// 777.963 us; speedup vs baseline: 1.0643x; 1.0643x over previous
//
#include <hip/hip_runtime.h>
#include <hip/hip_bf16.h>

// RGCN: N=4096, D=128, R=8, B=8, two layers + LN(+ReLU).
// R3: no atomics. agg writes per-(rowblk,kc) partial tiles (nontemporal,
// coalesced); fused reduce+LN kernel sums partials + self-loop base.
// Packed bf16 adj + nibble edge-types. Tiered ws fallback.

#define NN 4096
#define DD 128

typedef __attribute__((ext_vector_type(8))) short  s16x8;   // storage for 8 bf16
typedef __attribute__((ext_vector_type(8))) __bf16 bf16v8;  // MFMA operand type
typedef __attribute__((ext_vector_type(4))) float  f32x4;
typedef __attribute__((ext_vector_type(4))) int    i32x4;

__device__ inline short f2bf(float f) {            // f32 -> bf16 bits, RNE
  union { float f; unsigned u; } v; v.f = f;
  unsigned r = (v.u + 0x7FFFu + ((v.u >> 16) & 1u)) >> 16;
  return (short)r;
}

__device__ inline f32x4 mfma16(s16x8 a, s16x8 b, f32x4 c) {
  return __builtin_amdgcn_mfma_f32_16x16x32_bf16(
      __builtin_bit_cast(bf16v8, a), __builtin_bit_cast(bf16v8, b), c, 0, 0, 0);
}

// ---------------------------------------------------------------------------
// K0: pack adj (f32 -> bf16) and edge_type (i32 -> 4-bit nibbles, 8 per u32).
// ---------------------------------------------------------------------------
__global__ void pack_kernel(const float* __restrict__ adj, const int* __restrict__ et,
                            short* __restrict__ adjb, unsigned* __restrict__ etp) {
  int g = blockIdx.x * 256 + threadIdx.x;     // 0 .. 2M-1
  size_t base = (size_t)g * 8;
  f32x4 f0 = *(const f32x4*)(adj + base);
  f32x4 f1 = *(const f32x4*)(adj + base + 4);
  i32x4 e0 = *(const i32x4*)(et + base);
  i32x4 e1 = *(const i32x4*)(et + base + 4);
  short v[8];
#pragma unroll
  for (int e = 0; e < 4; ++e) v[e] = f2bf(f0[e]);
#pragma unroll
  for (int e = 0; e < 4; ++e) v[4 + e] = f2bf(f1[e]);
  unsigned pk = 0;
#pragma unroll
  for (int e = 0; e < 4; ++e) pk |= ((unsigned)e0[e] & 7u) << (4 * e);
#pragma unroll
  for (int e = 0; e < 4; ++e) pk |= ((unsigned)e1[e] & 7u) << (4 * (e + 4));
  *(s16x8*)(adjb + base) = *(s16x8*)v;
  etp[g] = pk;
}

// ---------------------------------------------------------------------------
// K1: w_r = sum_b weights[r,b]*bases[b] (r==8 -> W_self), pre-fragmented
// B-frags: [layer][r(9)][s(4)][t(8)][lane(64)][e(8)],
// elem = w[i = 32s+8*(l>>4)+e][o = 16t+(l&15)].
// ---------------------------------------------------------------------------
__global__ void prep_w(const float* __restrict__ b1, const float* __restrict__ w1,
                       const float* __restrict__ ws1,
                       const float* __restrict__ b2, const float* __restrict__ w2,
                       const float* __restrict__ ws2,
                       short* __restrict__ wfrag) {
  int tid = blockIdx.x * 256 + threadIdx.x;   // 0..36863 (2 layers x 18432)
  int layer = (tid >= 18432);
  int t0 = tid - layer * 18432;
  int lane = t0 & 63;
  int t = (t0 >> 6) & 7;
  int s = (t0 >> 9) & 3;
  int r = t0 >> 11;                            // 0..8
  const float* bases = layer ? b2 : b1;
  const float* wts   = layer ? w2 : w1;
  const float* wself = layer ? ws2 : ws1;
  int o  = t * 16 + (lane & 15);
  int i0 = s * 32 + 8 * (lane >> 4);
  short v[8];
#pragma unroll
  for (int e = 0; e < 8; ++e) {
    int i = i0 + e;
    float a;
    if (r < 8) {
      a = 0.f;
#pragma unroll
      for (int b = 0; b < 8; ++b)
        a += wts[r * 8 + b] * bases[((size_t)b * 128 + i) * 128 + o];
    } else {
      a = wself[(size_t)i * 128 + o];
    }
    v[e] = f2bf(a);
  }
  *(s16x8*)(wfrag + (size_t)tid * 8) = *(s16x8*)v;
}

// ---------------------------------------------------------------------------
// K2: xw_r = xin @ w_r for r=0..7 -> xwfrag (agg B-frag layout)
//     [r][mstep(128)][t(8)][lane(64)][e(8)]
//     r==8: hacc = xin @ W_self + bias (f32; base term for reduce)
// ---------------------------------------------------------------------------
__global__ void xw_gemm(const float* __restrict__ xin, const short* __restrict__ wfrag,
                        short* __restrict__ xwfrag, float* __restrict__ hacc,
                        const float* __restrict__ bias) {
  __shared__ short lds[4][32 * 128];
  int w = threadIdx.x >> 6, lane = threadIdx.x & 63;
  int widx = blockIdx.x * 4 + w;   // 0..1151
  int m = widx & 127;              // 32-row tile
  int r = widx >> 7;               // 0..8
  int l15 = lane & 15, l4 = lane >> 4;

  f32x4 acc[2][8] = {};

#pragma unroll
  for (int s = 0; s < 4; ++s) {
    s16x8 A[2];
#pragma unroll
    for (int nt = 0; nt < 2; ++nt) {
      const float* xp = xin + (size_t)(m * 32 + nt * 16 + l15) * 128 + s * 32 + 8 * l4;
      f32x4 f0 = *(const f32x4*)xp;
      f32x4 f1 = *(const f32x4*)(xp + 4);
      s16x8 av;
#pragma unroll
      for (int e = 0; e < 4; ++e) av[e] = f2bf(f0[e]);
#pragma unroll
      for (int e = 0; e < 4; ++e) av[4 + e] = f2bf(f1[e]);
      A[nt] = av;
    }
    const short* bp = wfrag + ((size_t)(r * 4 + s) * 8) * 512 + lane * 8;
#pragma unroll
    for (int t = 0; t < 8; ++t) {
      s16x8 B = *(const s16x8*)(bp + t * 512);
      acc[0][t] = mfma16(A[0], B, acc[0][t]);
      acc[1][t] = mfma16(A[1], B, acc[1][t]);
    }
  }

  if (r == 8) {
#pragma unroll
    for (int nt = 0; nt < 2; ++nt)
#pragma unroll
      for (int t = 0; t < 8; ++t)
#pragma unroll
        for (int j = 0; j < 4; ++j) {
          int row = m * 32 + nt * 16 + 4 * l4 + j;
          int col = t * 16 + l15;
          hacc[(size_t)row * 128 + col] = acc[nt][t][j] + bias[col];
        }
  } else {
#pragma unroll
    for (int nt = 0; nt < 2; ++nt)
#pragma unroll
      for (int t = 0; t < 8; ++t)
#pragma unroll
        for (int j = 0; j < 4; ++j)
          lds[w][(nt * 16 + 4 * l4 + j) * 128 + t * 16 + l15] = f2bf(acc[nt][t][j]);
    __syncthreads();
#pragma unroll
    for (int t = 0; t < 8; ++t) {
      short v[8];
#pragma unroll
      for (int e = 0; e < 8; ++e) v[e] = lds[w][(8 * l4 + e) * 128 + t * 16 + l15];
      *(s16x8*)(xwfrag + ((size_t)(r * 128 + m) * 8 + t) * 512 + lane * 8) = *(s16x8*)v;
    }
  }
}

// ---------------------------------------------------------------------------
// K3: partial[kc][rowblk] = sum_r (adj .* (et==r))[rows, kchunk] @ xw_r[kchunk]
// Grid dim3(KC, 32): blockIdx.x = kc (same-kc blocks share XCD when KC%8==0),
// blockIdx.y = rowblk. Block = 4 waves, 128x128 tile (wave 64x64). Plain
// nontemporal stores to a private tile -> zero contention.
// ---------------------------------------------------------------------------
template <bool PACKED>
__launch_bounds__(256, 4)
__global__ void agg_kernel(const float* __restrict__ adj, const int* __restrict__ et,
                           const short* __restrict__ adjb, const unsigned* __restrict__ etp,
                           const short* __restrict__ xwfrag, float* __restrict__ partial,
                           int msteps) {
  int w = threadIdx.x >> 6, lane = threadIdx.x & 63;
  int kc = blockIdx.x;
  int rowblk = blockIdx.y;
  int wr = w >> 1, wc = w & 1;
  int rowbase = rowblk * 128 + wr * 64;
  int l15 = lane & 15, l4 = lane >> 4;

  f32x4 acc[4][4] = {};

  for (int ms = 0; ms < msteps; ++ms) {
    int gm = kc * msteps + ms;       // global 32-wide m-step
    s16x8 a[4]; s16x8 cd[4];
#pragma unroll
    for (int nt = 0; nt < 4; ++nt) {
      size_t row = (size_t)(rowbase + nt * 16 + l15);
      if (PACKED) {
        a[nt] = *(const s16x8*)(adjb + row * 4096 + gm * 32 + 8 * l4);
        unsigned pk = etp[row * 512 + gm * 4 + l4];
        s16x8 c;
#pragma unroll
        for (int e = 0; e < 8; ++e) c[e] = (short)((pk >> (4 * e)) & 7u);
        cd[nt] = c;
      } else {
        size_t rbase = row * 4096 + gm * 32 + 8 * l4;
        f32x4 f0 = *(const f32x4*)(adj + rbase);
        f32x4 f1 = *(const f32x4*)(adj + rbase + 4);
        i32x4 e0 = *(const i32x4*)(et + rbase);
        i32x4 e1 = *(const i32x4*)(et + rbase + 4);
        s16x8 av, c;
#pragma unroll
        for (int e = 0; e < 4; ++e) { av[e] = f2bf(f0[e]); c[e] = (short)e0[e]; }
#pragma unroll
        for (int e = 0; e < 4; ++e) { av[4 + e] = f2bf(f1[e]); c[4 + e] = (short)e1[e]; }
        a[nt] = av; cd[nt] = c;
      }
    }
#pragma unroll
    for (int r = 0; r < 8; ++r) {
      const short* bp = xwfrag + ((size_t)((r * 128 + gm) * 8 + wc * 4)) * 512 + lane * 8;
      s16x8 b[4];
#pragma unroll
      for (int t = 0; t < 4; ++t) b[t] = *(const s16x8*)(bp + t * 512);
#pragma unroll
      for (int nt = 0; nt < 4; ++nt) {
        s16x8 mfr;
#pragma unroll
        for (int e = 0; e < 8; ++e) mfr[e] = (cd[nt][e] == (short)r) ? a[nt][e] : (short)0;
#pragma unroll
        for (int t = 0; t < 4; ++t)
          acc[nt][t] = mfma16(mfr, b[t], acc[nt][t]);
      }
    }
  }

  // epilogue: plain coalesced stores into this block's private tile
  float* tile = partial + ((size_t)kc * 32 + rowblk) * 16384;
#pragma unroll
  for (int nt = 0; nt < 4; ++nt)
#pragma unroll
    for (int t = 0; t < 4; ++t)
#pragma unroll
      for (int j = 0; j < 4; ++j) {
        int row = wr * 64 + nt * 16 + 4 * l4 + j;
        int col = wc * 64 + t * 16 + l15;
        __builtin_nontemporal_store(acc[nt][t][j], &tile[(size_t)row * 128 + col]);
      }
}

// ---------------------------------------------------------------------------
// K4: out = LN( hacc + sum_kc partial[kc] ) (+ReLU). One wave per row.
// ---------------------------------------------------------------------------
__global__ void reduce_ln(const float* __restrict__ partial, int KC,
                          const float* __restrict__ hacc,
                          const float* __restrict__ gamma, const float* __restrict__ beta,
                          float* __restrict__ out, int relu) {
  int row  = blockIdx.x * 4 + (threadIdx.x >> 6);
  int lane = threadIdx.x & 63;
  int rowblk = row >> 7, rl = row & 127;
  int c = lane * 2;
  float2 v = *(const float2*)&hacc[(size_t)row * 128 + c];
  float s0 = v.x, s1 = v.y;
  for (int kc = 0; kc < KC; ++kc) {
    const float* p = partial + ((size_t)kc * 32 + rowblk) * 16384 + (size_t)rl * 128 + c;
    float2 q = *(const float2*)p;
    s0 += q.x; s1 += q.y;
  }
  float s  = s0 + s1;
  float sq = s0 * s0 + s1 * s1;
#pragma unroll
  for (int off = 32; off; off >>= 1) {
    s  += __shfl_xor(s,  off);
    sq += __shfl_xor(sq, off);
  }
  float mu  = s * (1.f / 128.f);
  float var = sq * (1.f / 128.f) - mu * mu;
  float inv = rsqrtf(var + 1e-5f);
  float y0 = (s0 - mu) * inv * gamma[c]     + beta[c];
  float y1 = (s1 - mu) * inv * gamma[c + 1] + beta[c + 1];
  if (relu) { y0 = fmaxf(y0, 0.f); y1 = fmaxf(y1, 0.f); }
  float2 o; o.x = y0; o.y = y1;
  *(float2*)&out[(size_t)row * 128 + c] = o;
}

// ---------------------------------------------------------------------------
extern "C" void kernel_launch(void* const* d_in, const int* in_sizes, int n_in,
                              void* d_out, int out_size, void* d_ws, size_t ws_size,
                              hipStream_t stream) {
  const float* x      = (const float*)d_in[0];
  const float* adj    = (const float*)d_in[1];
  const int*   et     = (const int*)d_in[2];
  const float* bases1 = (const float*)d_in[3];
  const float* wts1   = (const float*)d_in[4];
  const float* wself1 = (const float*)d_in[5];
  const float* bself1 = (const float*)d_in[6];
  const float* bases2 = (const float*)d_in[7];
  const float* wts2   = (const float*)d_in[8];
  const float* wself2 = (const float*)d_in[9];
  const float* bself2 = (const float*)d_in[10];
  const float* gamma1 = (const float*)d_in[11];
  const float* beta1  = (const float*)d_in[12];
  const float* gamma2 = (const float*)d_in[13];
  const float* beta2  = (const float*)d_in[14];

  char* ws = (char*)d_ws;
  const size_t BASE = 589824ull + 8388608ull + 2097152ull + 2097152ull; // 13,172,736
  short* wfrag  = (short*)(ws);
  short* xwfrag = (short*)(ws + 589824);
  float* hacc   = (float*)(ws + 589824 + 8388608);
  float* h1     = (float*)(ws + 589824 + 8388608 + 2097152);

  // tier selection: partials (KC * 2 MiB) after BASE; packed buffers after that
  const size_t PACKSZ = 33554432ull + 8388608ull;   // adjb + etp
  int KC = 0; bool packed = false;
  {
    const int ptiers[3] = {32, 16, 8};
    for (int i = 0; i < 3 && !KC; ++i)
      if (ws_size >= BASE + (size_t)ptiers[i] * 2097152ull + PACKSZ) { KC = ptiers[i]; packed = true; }
    const int utiers[5] = {16, 8, 4, 2, 1};
    for (int i = 0; i < 5 && !KC; ++i)
      if (ws_size >= BASE + (size_t)utiers[i] * 2097152ull) KC = utiers[i];
    if (!KC) KC = 1;
  }
  float*    partial = (float*)(ws + BASE);
  short*    adjb    = (short*)(ws + BASE + (size_t)KC * 2097152ull);
  unsigned* etp     = (unsigned*)(ws + BASE + (size_t)KC * 2097152ull + 33554432ull);
  int msteps = 128 / KC;

  prep_w<<<144, 256, 0, stream>>>(bases1, wts1, wself1, bases2, wts2, wself2, wfrag);
  if (packed)
    pack_kernel<<<8192, 256, 0, stream>>>(adj, et, adjb, etp);

  dim3 agrid(KC, 32);

  // layer 1
  xw_gemm<<<288, 256, 0, stream>>>(x, wfrag, xwfrag, hacc, bself1);
  if (packed)
    agg_kernel<true ><<<agrid, 256, 0, stream>>>(adj, et, adjb, etp, xwfrag, partial, msteps);
  else
    agg_kernel<false><<<agrid, 256, 0, stream>>>(adj, et, adjb, etp, xwfrag, partial, msteps);
  reduce_ln<<<1024, 256, 0, stream>>>(partial, KC, hacc, gamma1, beta1, h1, 1);

  // layer 2
  xw_gemm<<<288, 256, 0, stream>>>(h1, wfrag + 147456, xwfrag, hacc, bself2);
  if (packed)
    agg_kernel<true ><<<agrid, 256, 0, stream>>>(adj, et, adjb, etp, xwfrag, partial, msteps);
  else
    agg_kernel<false><<<agrid, 256, 0, stream>>>(adj, et, adjb, etp, xwfrag, partial, msteps);
  reduce_ln<<<1024, 256, 0, stream>>>(partial, KC, hacc, gamma2, beta2, (float*)d_out, 0);
}

// Round 4
// 284.707 us; speedup vs baseline: 2.9083x; 2.7325x over previous
//
#include <hip/hip_runtime.h>
#include <hip/hip_bf16.h>

// RGCN: N=4096, D=128, R=8, B=8, two layers + LN(+ReLU).
// R4: traffic-clean agg: lane-contiguous f32x4 partial stores (nontemporal,
// full-line), nontemporal streaming loads for adj/et (protect L2-resident
// xwfrag), etp repacked for one-i32x4-per-lane k-chunk loads.

#define NN 4096
#define DD 128

typedef __attribute__((ext_vector_type(8))) short  s16x8;   // storage for 8 bf16
typedef __attribute__((ext_vector_type(8))) __bf16 bf16v8;  // MFMA operand type
typedef __attribute__((ext_vector_type(4))) float  f32x4;
typedef __attribute__((ext_vector_type(4))) int    i32x4;

__device__ inline short f2bf(float f) {            // f32 -> bf16 bits, RNE
  union { float f; unsigned u; } v; v.f = f;
  unsigned r = (v.u + 0x7FFFu + ((v.u >> 16) & 1u)) >> 16;
  return (short)r;
}

__device__ inline f32x4 mfma16(s16x8 a, s16x8 b, f32x4 c) {
  return __builtin_amdgcn_mfma_f32_16x16x32_bf16(
      __builtin_bit_cast(bf16v8, a), __builtin_bit_cast(bf16v8, b), c, 0, 0, 0);
}

// ---------------------------------------------------------------------------
// K0: pack adj (f32 -> bf16) and edge_type (i32 -> 4-bit nibbles, 8 per u32).
// etp u32s are permuted within each 16-u32 (64B) group: (hi2,lo2)->(lo2,hi2)
// so agg lane (l4) can load its 4-ms nibble words as one contiguous i32x4.
// ---------------------------------------------------------------------------
__global__ void pack_kernel(const float* __restrict__ adj, const int* __restrict__ et,
                            short* __restrict__ adjb, unsigned* __restrict__ etp) {
  int g = blockIdx.x * 256 + threadIdx.x;     // linear u32 index, 0 .. 2M-1
  size_t base = (size_t)g * 8;
  f32x4 f0 = *(const f32x4*)(adj + base);
  f32x4 f1 = *(const f32x4*)(adj + base + 4);
  i32x4 e0 = *(const i32x4*)(et + base);
  i32x4 e1 = *(const i32x4*)(et + base + 4);
  short v[8];
#pragma unroll
  for (int e = 0; e < 4; ++e) v[e] = f2bf(f0[e]);
#pragma unroll
  for (int e = 0; e < 4; ++e) v[4 + e] = f2bf(f1[e]);
  unsigned pk = 0;
#pragma unroll
  for (int e = 0; e < 4; ++e) pk |= ((unsigned)e0[e] & 7u) << (4 * e);
#pragma unroll
  for (int e = 0; e < 4; ++e) pk |= ((unsigned)e1[e] & 7u) << (4 * (e + 4));
  *(s16x8*)(adjb + base) = *(s16x8*)v;
  int m8 = g & 511, row = g >> 9;
  int np = (m8 & ~15) | ((m8 & 3) << 2) | ((m8 >> 2) & 3);
  etp[(size_t)row * 512 + np] = pk;
}

// ---------------------------------------------------------------------------
// K1: w_r = sum_b weights[r,b]*bases[b] (r==8 -> W_self), pre-fragmented
// B-frags: [layer][r(9)][s(4)][t(8)][lane(64)][e(8)],
// elem = w[i = 32s+8*(l>>4)+e][o = 16t+(l&15)].
// ---------------------------------------------------------------------------
__global__ void prep_w(const float* __restrict__ b1, const float* __restrict__ w1,
                       const float* __restrict__ ws1,
                       const float* __restrict__ b2, const float* __restrict__ w2,
                       const float* __restrict__ ws2,
                       short* __restrict__ wfrag) {
  int tid = blockIdx.x * 256 + threadIdx.x;   // 0..36863 (2 layers x 18432)
  int layer = (tid >= 18432);
  int t0 = tid - layer * 18432;
  int lane = t0 & 63;
  int t = (t0 >> 6) & 7;
  int s = (t0 >> 9) & 3;
  int r = t0 >> 11;                            // 0..8
  const float* bases = layer ? b2 : b1;
  const float* wts   = layer ? w2 : w1;
  const float* wself = layer ? ws2 : ws1;
  int o  = t * 16 + (lane & 15);
  int i0 = s * 32 + 8 * (lane >> 4);
  short v[8];
#pragma unroll
  for (int e = 0; e < 8; ++e) {
    int i = i0 + e;
    float a;
    if (r < 8) {
      a = 0.f;
#pragma unroll
      for (int b = 0; b < 8; ++b)
        a += wts[r * 8 + b] * bases[((size_t)b * 128 + i) * 128 + o];
    } else {
      a = wself[(size_t)i * 128 + o];
    }
    v[e] = f2bf(a);
  }
  *(s16x8*)(wfrag + (size_t)tid * 8) = *(s16x8*)v;
}

// ---------------------------------------------------------------------------
// K2: xw_r = xin @ w_r for r=0..7 -> xwfrag (agg B-frag layout)
//     [r][mstep(128)][t(8)][lane(64)][e(8)]
//     r==8: hacc = xin @ W_self + bias (f32; base term for reduce)
// ---------------------------------------------------------------------------
__global__ void xw_gemm(const float* __restrict__ xin, const short* __restrict__ wfrag,
                        short* __restrict__ xwfrag, float* __restrict__ hacc,
                        const float* __restrict__ bias) {
  __shared__ short lds[4][32 * 128];
  int w = threadIdx.x >> 6, lane = threadIdx.x & 63;
  int widx = blockIdx.x * 4 + w;   // 0..1151
  int m = widx & 127;              // 32-row tile
  int r = widx >> 7;               // 0..8
  int l15 = lane & 15, l4 = lane >> 4;

  f32x4 acc[2][8] = {};

#pragma unroll
  for (int s = 0; s < 4; ++s) {
    s16x8 A[2];
#pragma unroll
    for (int nt = 0; nt < 2; ++nt) {
      const float* xp = xin + (size_t)(m * 32 + nt * 16 + l15) * 128 + s * 32 + 8 * l4;
      f32x4 f0 = *(const f32x4*)xp;
      f32x4 f1 = *(const f32x4*)(xp + 4);
      s16x8 av;
#pragma unroll
      for (int e = 0; e < 4; ++e) av[e] = f2bf(f0[e]);
#pragma unroll
      for (int e = 0; e < 4; ++e) av[4 + e] = f2bf(f1[e]);
      A[nt] = av;
    }
    const short* bp = wfrag + ((size_t)(r * 4 + s) * 8) * 512 + lane * 8;
#pragma unroll
    for (int t = 0; t < 8; ++t) {
      s16x8 B = *(const s16x8*)(bp + t * 512);
      acc[0][t] = mfma16(A[0], B, acc[0][t]);
      acc[1][t] = mfma16(A[1], B, acc[1][t]);
    }
  }

  if (r == 8) {
#pragma unroll
    for (int nt = 0; nt < 2; ++nt)
#pragma unroll
      for (int t = 0; t < 8; ++t)
#pragma unroll
        for (int j = 0; j < 4; ++j) {
          int row = m * 32 + nt * 16 + 4 * l4 + j;
          int col = t * 16 + l15;
          hacc[(size_t)row * 128 + col] = acc[nt][t][j] + bias[col];
        }
  } else {
#pragma unroll
    for (int nt = 0; nt < 2; ++nt)
#pragma unroll
      for (int t = 0; t < 8; ++t)
#pragma unroll
        for (int j = 0; j < 4; ++j)
          lds[w][(nt * 16 + 4 * l4 + j) * 128 + t * 16 + l15] = f2bf(acc[nt][t][j]);
    __syncthreads();
#pragma unroll
    for (int t = 0; t < 8; ++t) {
      short v[8];
#pragma unroll
      for (int e = 0; e < 8; ++e) v[e] = lds[w][(8 * l4 + e) * 128 + t * 16 + l15];
      *(s16x8*)(xwfrag + ((size_t)(r * 128 + m) * 8 + t) * 512 + lane * 8) = *(s16x8*)v;
    }
  }
}

// ---------------------------------------------------------------------------
// K3: partial[kc][rowblk] = sum_r (adj .* (et==r))[rows, kchunk] @ xw_r[kchunk]
// Grid dim3(KC,32): x=kc (pins kc%8 to one XCD -> its xwfrag slice stays in
// that L2), y=rowblk. Block = 4 waves, 128x128 tile (wave 64x64).
// Partial tile layout: [w][nt][t][lane][4] f32 — lane-contiguous f32x4 stores,
// each wave store instr = 1KB contiguous (full lines), nontemporal.
// ---------------------------------------------------------------------------
template <bool PACKED>
__launch_bounds__(256, 3)
__global__ void agg_kernel(const float* __restrict__ adj, const int* __restrict__ et,
                           const short* __restrict__ adjb, const unsigned* __restrict__ etp,
                           const short* __restrict__ xwfrag, float* __restrict__ partial,
                           int msteps) {
  int w = threadIdx.x >> 6, lane = threadIdx.x & 63;
  int kc = blockIdx.x;
  int rowblk = blockIdx.y;
  int wr = w >> 1, wc = w & 1;
  int rowbase = rowblk * 128 + wr * 64;
  int l15 = lane & 15, l4 = lane >> 4;

  f32x4 acc[4][4] = {};

  if constexpr (PACKED) {
    // per-row nibble words for the whole kc-chunk, one i32x4 per (nt)
    i32x4 V[4];
#pragma unroll
    for (int nt = 0; nt < 4; ++nt) {
      size_t row = (size_t)(rowbase + nt * 16 + l15);
      V[nt] = __builtin_nontemporal_load(
          (const i32x4*)(etp + row * 512 + kc * 16 + l4 * 4));
    }
#pragma unroll
    for (int ms = 0; ms < 4; ++ms) {
      int gm = kc * 4 + ms;
      s16x8 a[4]; s16x8 cd[4];
#pragma unroll
      for (int nt = 0; nt < 4; ++nt) {
        size_t row = (size_t)(rowbase + nt * 16 + l15);
        a[nt] = __builtin_nontemporal_load(
            (const s16x8*)(adjb + row * 4096 + gm * 32 + 8 * l4));
        unsigned pk = (unsigned)V[nt][ms];
        s16x8 c;
#pragma unroll
        for (int e = 0; e < 8; ++e) c[e] = (short)((pk >> (4 * e)) & 7u);
        cd[nt] = c;
      }
#pragma unroll
      for (int r = 0; r < 8; ++r) {
        const short* bp = xwfrag + ((size_t)((r * 128 + gm) * 8 + wc * 4)) * 512 + lane * 8;
        s16x8 b[4];
#pragma unroll
        for (int t = 0; t < 4; ++t) b[t] = *(const s16x8*)(bp + t * 512);
#pragma unroll
        for (int nt = 0; nt < 4; ++nt) {
          s16x8 mfr;
#pragma unroll
          for (int e = 0; e < 8; ++e) mfr[e] = (cd[nt][e] == (short)r) ? a[nt][e] : (short)0;
#pragma unroll
          for (int t = 0; t < 4; ++t)
            acc[nt][t] = mfma16(mfr, b[t], acc[nt][t]);
        }
      }
    }
  } else {
    for (int ms = 0; ms < msteps; ++ms) {
      int gm = kc * msteps + ms;
      s16x8 a[4]; s16x8 cd[4];
#pragma unroll
      for (int nt = 0; nt < 4; ++nt) {
        size_t rbase = (size_t)(rowbase + nt * 16 + l15) * 4096 + gm * 32 + 8 * l4;
        f32x4 f0 = __builtin_nontemporal_load((const f32x4*)(adj + rbase));
        f32x4 f1 = __builtin_nontemporal_load((const f32x4*)(adj + rbase + 4));
        i32x4 e0 = __builtin_nontemporal_load((const i32x4*)(et + rbase));
        i32x4 e1 = __builtin_nontemporal_load((const i32x4*)(et + rbase + 4));
        s16x8 av, c;
#pragma unroll
        for (int e = 0; e < 4; ++e) { av[e] = f2bf(f0[e]); c[e] = (short)e0[e]; }
#pragma unroll
        for (int e = 0; e < 4; ++e) { av[4 + e] = f2bf(f1[e]); c[4 + e] = (short)e1[e]; }
        a[nt] = av; cd[nt] = c;
      }
#pragma unroll
      for (int r = 0; r < 8; ++r) {
        const short* bp = xwfrag + ((size_t)((r * 128 + gm) * 8 + wc * 4)) * 512 + lane * 8;
        s16x8 b[4];
#pragma unroll
        for (int t = 0; t < 4; ++t) b[t] = *(const s16x8*)(bp + t * 512);
#pragma unroll
        for (int nt = 0; nt < 4; ++nt) {
          s16x8 mfr;
#pragma unroll
          for (int e = 0; e < 8; ++e) mfr[e] = (cd[nt][e] == (short)r) ? a[nt][e] : (short)0;
#pragma unroll
          for (int t = 0; t < 4; ++t)
            acc[nt][t] = mfma16(mfr, b[t], acc[nt][t]);
        }
      }
    }
  }

  // epilogue: lane-contiguous f32x4 stores — wave instr = 1KB contiguous
  float* tile = partial + ((size_t)kc * 32 + rowblk) * 16384;
#pragma unroll
  for (int nt = 0; nt < 4; ++nt)
#pragma unroll
    for (int t = 0; t < 4; ++t)
      __builtin_nontemporal_store(
          acc[nt][t], (f32x4*)(tile + (size_t)(((w * 4 + nt) * 4 + t) * 256 + lane * 4)));
}

// ---------------------------------------------------------------------------
// K4: out = LN( hacc + sum_kc partial[kc] ) (+ReLU).
// Wave handles 4 consecutive rows (one stored quad); lane holds 2 cols x 4 rows.
// Partial gathers are dwordx4, contiguous across 16-lane groups.
// ---------------------------------------------------------------------------
__global__ void reduce_ln(const float* __restrict__ partial, int KC,
                          const float* __restrict__ hacc,
                          const float* __restrict__ gamma, const float* __restrict__ beta,
                          float* __restrict__ out, int relu) {
  int lane = threadIdx.x & 63;
  int g = blockIdx.x * 4 + (threadIdx.x >> 6);   // row-quad id, 0..1023
  int rowblk = g >> 5;
  int qin = g & 31;
  int wr = qin >> 4, nt = (qin >> 2) & 3, l4 = qin & 3;
  int rowbase = rowblk * 128 + wr * 64 + nt * 16 + l4 * 4;

  int c0 = lane, c1 = lane + 64;
  f32x4 v0, v1;
#pragma unroll
  for (int j = 0; j < 4; ++j) {
    v0[j] = hacc[(size_t)(rowbase + j) * 128 + c0];
    v1[j] = hacc[(size_t)(rowbase + j) * 128 + c1];
  }
  int t = (lane >> 4) & 3;
  size_t off0 = (size_t)(((wr * 2 + 0) * 4 + nt) * 4 + t) * 256 + (l4 * 16 + (lane & 15)) * 4;
  size_t off1 = (size_t)(((wr * 2 + 1) * 4 + nt) * 4 + t) * 256 + (l4 * 16 + (lane & 15)) * 4;
  for (int kc = 0; kc < KC; ++kc) {
    const float* tile = partial + ((size_t)kc * 32 + rowblk) * 16384;
    f32x4 p0 = *(const f32x4*)(tile + off0);
    f32x4 p1 = *(const f32x4*)(tile + off1);
#pragma unroll
    for (int j = 0; j < 4; ++j) { v0[j] += p0[j]; v1[j] += p1[j]; }
  }

  f32x4 s, sq;
#pragma unroll
  for (int j = 0; j < 4; ++j) {
    s[j]  = v0[j] + v1[j];
    sq[j] = v0[j] * v0[j] + v1[j] * v1[j];
  }
#pragma unroll
  for (int off = 32; off; off >>= 1) {
#pragma unroll
    for (int j = 0; j < 4; ++j) {
      s[j]  += __shfl_xor(s[j],  off);
      sq[j] += __shfl_xor(sq[j], off);
    }
  }
  float g0 = gamma[c0], g1 = gamma[c1], b0 = beta[c0], b1 = beta[c1];
#pragma unroll
  for (int j = 0; j < 4; ++j) {
    float mu  = s[j] * (1.f / 128.f);
    float var = sq[j] * (1.f / 128.f) - mu * mu;
    float inv = rsqrtf(var + 1e-5f);
    float y0 = (v0[j] - mu) * inv * g0 + b0;
    float y1 = (v1[j] - mu) * inv * g1 + b1;
    if (relu) { y0 = fmaxf(y0, 0.f); y1 = fmaxf(y1, 0.f); }
    out[(size_t)(rowbase + j) * 128 + c0] = y0;
    out[(size_t)(rowbase + j) * 128 + c1] = y1;
  }
}

// ---------------------------------------------------------------------------
extern "C" void kernel_launch(void* const* d_in, const int* in_sizes, int n_in,
                              void* d_out, int out_size, void* d_ws, size_t ws_size,
                              hipStream_t stream) {
  const float* x      = (const float*)d_in[0];
  const float* adj    = (const float*)d_in[1];
  const int*   et     = (const int*)d_in[2];
  const float* bases1 = (const float*)d_in[3];
  const float* wts1   = (const float*)d_in[4];
  const float* wself1 = (const float*)d_in[5];
  const float* bself1 = (const float*)d_in[6];
  const float* bases2 = (const float*)d_in[7];
  const float* wts2   = (const float*)d_in[8];
  const float* wself2 = (const float*)d_in[9];
  const float* bself2 = (const float*)d_in[10];
  const float* gamma1 = (const float*)d_in[11];
  const float* beta1  = (const float*)d_in[12];
  const float* gamma2 = (const float*)d_in[13];
  const float* beta2  = (const float*)d_in[14];

  char* ws = (char*)d_ws;
  const size_t BASE = 589824ull + 8388608ull + 2097152ull + 2097152ull; // 13,172,736
  short* wfrag  = (short*)(ws);
  short* xwfrag = (short*)(ws + 589824);
  float* hacc   = (float*)(ws + 589824 + 8388608);
  float* h1     = (float*)(ws + 589824 + 8388608 + 2097152);

  // tier selection: partials (KC * 2 MiB) after BASE; packed buffers after that
  const size_t PACKSZ = 33554432ull + 8388608ull;   // adjb + etp
  int KC = 0; bool packed = false;
  if (ws_size >= BASE + 32ull * 2097152ull + PACKSZ) { KC = 32; packed = true; }
  if (!KC) {
    const int utiers[5] = {16, 8, 4, 2, 1};
    for (int i = 0; i < 5 && !KC; ++i)
      if (ws_size >= BASE + (size_t)utiers[i] * 2097152ull) KC = utiers[i];
    if (!KC) KC = 1;
  }
  float*    partial = (float*)(ws + BASE);
  short*    adjb    = (short*)(ws + BASE + (size_t)KC * 2097152ull);
  unsigned* etp     = (unsigned*)(ws + BASE + (size_t)KC * 2097152ull + 33554432ull);
  int msteps = 128 / KC;

  prep_w<<<144, 256, 0, stream>>>(bases1, wts1, wself1, bases2, wts2, wself2, wfrag);
  if (packed)
    pack_kernel<<<8192, 256, 0, stream>>>(adj, et, adjb, etp);

  dim3 agrid(KC, 32);

  // layer 1
  xw_gemm<<<288, 256, 0, stream>>>(x, wfrag, xwfrag, hacc, bself1);
  if (packed)
    agg_kernel<true ><<<agrid, 256, 0, stream>>>(adj, et, adjb, etp, xwfrag, partial, msteps);
  else
    agg_kernel<false><<<agrid, 256, 0, stream>>>(adj, et, adjb, etp, xwfrag, partial, msteps);
  reduce_ln<<<256, 256, 0, stream>>>(partial, KC, hacc, gamma1, beta1, h1, 1);

  // layer 2
  xw_gemm<<<288, 256, 0, stream>>>(h1, wfrag + 147456, xwfrag, hacc, bself2);
  if (packed)
    agg_kernel<true ><<<agrid, 256, 0, stream>>>(adj, et, adjb, etp, xwfrag, partial, msteps);
  else
    agg_kernel<false><<<agrid, 256, 0, stream>>>(adj, et, adjb, etp, xwfrag, partial, msteps);
  reduce_ln<<<256, 256, 0, stream>>>(partial, KC, hacc, gamma2, beta2, (float*)d_out, 0);
}

// Round 5
// 267.850 us; speedup vs baseline: 3.0914x; 1.0629x over previous
//
#include <hip/hip_runtime.h>
#include <hip/hip_bf16.h>

// RGCN: N=4096, D=128, R=8, B=8, two layers + LN(+ReLU).
// R5: agg latency restructure — A/etp register prefetch pipeline (1-deep),
// hoisted nibble expansion, unrolled r-loop with independent b-loads.
// Traffic layout from R4 (lane-contiguous nontemporal partial stores).

#define NN 4096
#define DD 128

typedef __attribute__((ext_vector_type(8))) short  s16x8;   // storage for 8 bf16
typedef __attribute__((ext_vector_type(8))) __bf16 bf16v8;  // MFMA operand type
typedef __attribute__((ext_vector_type(4))) float  f32x4;
typedef __attribute__((ext_vector_type(4))) int    i32x4;

__device__ inline short f2bf(float f) {            // f32 -> bf16 bits, RNE
  union { float f; unsigned u; } v; v.f = f;
  unsigned r = (v.u + 0x7FFFu + ((v.u >> 16) & 1u)) >> 16;
  return (short)r;
}

__device__ inline f32x4 mfma16(s16x8 a, s16x8 b, f32x4 c) {
  return __builtin_amdgcn_mfma_f32_16x16x32_bf16(
      __builtin_bit_cast(bf16v8, a), __builtin_bit_cast(bf16v8, b), c, 0, 0, 0);
}

// ---------------------------------------------------------------------------
// K0: pack adj (f32 -> bf16) and edge_type (i32 -> 4-bit nibbles, 8 per u32).
// etp u32s permuted within each 16-u32 group so agg lane l4 loads its 4-ms
// nibble words as one contiguous i32x4.
// ---------------------------------------------------------------------------
__global__ void pack_kernel(const float* __restrict__ adj, const int* __restrict__ et,
                            short* __restrict__ adjb, unsigned* __restrict__ etp) {
  int g = blockIdx.x * 256 + threadIdx.x;     // linear u32 index, 0 .. 2M-1
  size_t base = (size_t)g * 8;
  f32x4 f0 = *(const f32x4*)(adj + base);
  f32x4 f1 = *(const f32x4*)(adj + base + 4);
  i32x4 e0 = *(const i32x4*)(et + base);
  i32x4 e1 = *(const i32x4*)(et + base + 4);
  short v[8];
#pragma unroll
  for (int e = 0; e < 4; ++e) v[e] = f2bf(f0[e]);
#pragma unroll
  for (int e = 0; e < 4; ++e) v[4 + e] = f2bf(f1[e]);
  unsigned pk = 0;
#pragma unroll
  for (int e = 0; e < 4; ++e) pk |= ((unsigned)e0[e] & 7u) << (4 * e);
#pragma unroll
  for (int e = 0; e < 4; ++e) pk |= ((unsigned)e1[e] & 7u) << (4 * (e + 4));
  *(s16x8*)(adjb + base) = *(s16x8*)v;
  int m8 = g & 511, row = g >> 9;
  int np = (m8 & ~15) | ((m8 & 3) << 2) | ((m8 >> 2) & 3);
  etp[(size_t)row * 512 + np] = pk;
}

// ---------------------------------------------------------------------------
// K1: w_r = sum_b weights[r,b]*bases[b] (r==8 -> W_self), pre-fragmented
// B-frags: [layer][r(9)][s(4)][t(8)][lane(64)][e(8)],
// elem = w[i = 32s+8*(l>>4)+e][o = 16t+(l&15)].
// ---------------------------------------------------------------------------
__global__ void prep_w(const float* __restrict__ b1, const float* __restrict__ w1,
                       const float* __restrict__ ws1,
                       const float* __restrict__ b2, const float* __restrict__ w2,
                       const float* __restrict__ ws2,
                       short* __restrict__ wfrag) {
  int tid = blockIdx.x * 256 + threadIdx.x;   // 0..36863 (2 layers x 18432)
  int layer = (tid >= 18432);
  int t0 = tid - layer * 18432;
  int lane = t0 & 63;
  int t = (t0 >> 6) & 7;
  int s = (t0 >> 9) & 3;
  int r = t0 >> 11;                            // 0..8
  const float* bases = layer ? b2 : b1;
  const float* wts   = layer ? w2 : w1;
  const float* wself = layer ? ws2 : ws1;
  int o  = t * 16 + (lane & 15);
  int i0 = s * 32 + 8 * (lane >> 4);
  short v[8];
#pragma unroll
  for (int e = 0; e < 8; ++e) {
    int i = i0 + e;
    float a;
    if (r < 8) {
      a = 0.f;
#pragma unroll
      for (int b = 0; b < 8; ++b)
        a += wts[r * 8 + b] * bases[((size_t)b * 128 + i) * 128 + o];
    } else {
      a = wself[(size_t)i * 128 + o];
    }
    v[e] = f2bf(a);
  }
  *(s16x8*)(wfrag + (size_t)tid * 8) = *(s16x8*)v;
}

// ---------------------------------------------------------------------------
// K2: xw_r = xin @ w_r for r=0..7 -> xwfrag (agg B-frag layout)
//     [r][mstep(128)][t(8)][lane(64)][e(8)]
//     r==8: hacc = xin @ W_self + bias (f32; base term for reduce)
// ---------------------------------------------------------------------------
__global__ void xw_gemm(const float* __restrict__ xin, const short* __restrict__ wfrag,
                        short* __restrict__ xwfrag, float* __restrict__ hacc,
                        const float* __restrict__ bias) {
  __shared__ short lds[4][32 * 128];
  int w = threadIdx.x >> 6, lane = threadIdx.x & 63;
  int widx = blockIdx.x * 4 + w;   // 0..1151
  int m = widx & 127;              // 32-row tile
  int r = widx >> 7;               // 0..8
  int l15 = lane & 15, l4 = lane >> 4;

  f32x4 acc[2][8] = {};

#pragma unroll
  for (int s = 0; s < 4; ++s) {
    s16x8 A[2];
#pragma unroll
    for (int nt = 0; nt < 2; ++nt) {
      const float* xp = xin + (size_t)(m * 32 + nt * 16 + l15) * 128 + s * 32 + 8 * l4;
      f32x4 f0 = *(const f32x4*)xp;
      f32x4 f1 = *(const f32x4*)(xp + 4);
      s16x8 av;
#pragma unroll
      for (int e = 0; e < 4; ++e) av[e] = f2bf(f0[e]);
#pragma unroll
      for (int e = 0; e < 4; ++e) av[4 + e] = f2bf(f1[e]);
      A[nt] = av;
    }
    const short* bp = wfrag + ((size_t)(r * 4 + s) * 8) * 512 + lane * 8;
#pragma unroll
    for (int t = 0; t < 8; ++t) {
      s16x8 B = *(const s16x8*)(bp + t * 512);
      acc[0][t] = mfma16(A[0], B, acc[0][t]);
      acc[1][t] = mfma16(A[1], B, acc[1][t]);
    }
  }

  if (r == 8) {
#pragma unroll
    for (int nt = 0; nt < 2; ++nt)
#pragma unroll
      for (int t = 0; t < 8; ++t)
#pragma unroll
        for (int j = 0; j < 4; ++j) {
          int row = m * 32 + nt * 16 + 4 * l4 + j;
          int col = t * 16 + l15;
          hacc[(size_t)row * 128 + col] = acc[nt][t][j] + bias[col];
        }
  } else {
#pragma unroll
    for (int nt = 0; nt < 2; ++nt)
#pragma unroll
      for (int t = 0; t < 8; ++t)
#pragma unroll
        for (int j = 0; j < 4; ++j)
          lds[w][(nt * 16 + 4 * l4 + j) * 128 + t * 16 + l15] = f2bf(acc[nt][t][j]);
    __syncthreads();
#pragma unroll
    for (int t = 0; t < 8; ++t) {
      short v[8];
#pragma unroll
      for (int e = 0; e < 8; ++e) v[e] = lds[w][(8 * l4 + e) * 128 + t * 16 + l15];
      *(s16x8*)(xwfrag + ((size_t)(r * 128 + m) * 8 + t) * 512 + lane * 8) = *(s16x8*)v;
    }
  }
}

// ---------------------------------------------------------------------------
// K3: partial[kc][rowblk] = sum_r (adj .* (et==r))[rows, kchunk] @ xw_r[kchunk]
// Grid dim3(KC,32). Block = 4 waves, 128x128 tile (wave 64x64).
// Pipeline: A[ms+1] HBM loads issued while computing ms; cd nibble expansion
// hoisted out of the r-loop; r-loop fully unrolled (b-loads overlap MFMA).
// ---------------------------------------------------------------------------
template <bool PACKED>
__launch_bounds__(256, 3)
__global__ void agg_kernel(const float* __restrict__ adj, const int* __restrict__ et,
                           const short* __restrict__ adjb, const unsigned* __restrict__ etp,
                           const short* __restrict__ xwfrag, float* __restrict__ partial,
                           int msteps) {
  int w = threadIdx.x >> 6, lane = threadIdx.x & 63;
  int kc = blockIdx.x;
  int rowblk = blockIdx.y;
  int wr = w >> 1, wc = w & 1;
  int rowbase = rowblk * 128 + wr * 64;
  int l15 = lane & 15, l4 = lane >> 4;

  f32x4 acc[4][4] = {};

  if constexpr (PACKED) {
    // per-nt base pointers for this kc chunk
    const short* ap[4];
    i32x4 V[4];
#pragma unroll
    for (int nt = 0; nt < 4; ++nt) {
      size_t row = (size_t)(rowbase + nt * 16 + l15);
      ap[nt] = adjb + row * 4096 + kc * 128 + 8 * l4;
      V[nt] = __builtin_nontemporal_load((const i32x4*)(etp + row * 512 + kc * 16 + l4 * 4));
    }
    // prefetch pipeline over ms: A[(ms)&1] in use, A[(ms+1)&1] loading
    s16x8 A[2][4];
#pragma unroll
    for (int nt = 0; nt < 4; ++nt)
      A[0][nt] = __builtin_nontemporal_load((const s16x8*)(ap[nt]));

#pragma unroll
    for (int ms = 0; ms < 4; ++ms) {
      int cur = ms & 1, nxt = cur ^ 1;
      if (ms < 3) {
#pragma unroll
        for (int nt = 0; nt < 4; ++nt)
          A[nxt][nt] = __builtin_nontemporal_load((const s16x8*)(ap[nt] + (ms + 1) * 32));
      }
      // hoisted nibble expansion (reused by all 8 relations)
      s16x8 cd[4];
#pragma unroll
      for (int nt = 0; nt < 4; ++nt) {
        unsigned pk = (unsigned)V[nt][ms];
        s16x8 c;
#pragma unroll
        for (int e = 0; e < 8; ++e) c[e] = (short)((pk >> (4 * e)) & 7u);
        cd[nt] = c;
      }
      int gm = kc * 4 + ms;
#pragma unroll
      for (int r = 0; r < 8; ++r) {
        const short* bp = xwfrag + ((size_t)((r * 128 + gm) * 8 + wc * 4)) * 512 + lane * 8;
        s16x8 b[4];
#pragma unroll
        for (int t = 0; t < 4; ++t) b[t] = *(const s16x8*)(bp + t * 512);
#pragma unroll
        for (int nt = 0; nt < 4; ++nt) {
          s16x8 mfr;
#pragma unroll
          for (int e = 0; e < 8; ++e) mfr[e] = (cd[nt][e] == (short)r) ? A[cur][nt][e] : (short)0;
#pragma unroll
          for (int t = 0; t < 4; ++t)
            acc[nt][t] = mfma16(mfr, b[t], acc[nt][t]);
        }
      }
    }
  } else {
    for (int ms = 0; ms < msteps; ++ms) {
      int gm = kc * msteps + ms;
      s16x8 a[4]; s16x8 cd[4];
#pragma unroll
      for (int nt = 0; nt < 4; ++nt) {
        size_t rbase = (size_t)(rowbase + nt * 16 + l15) * 4096 + gm * 32 + 8 * l4;
        f32x4 f0 = __builtin_nontemporal_load((const f32x4*)(adj + rbase));
        f32x4 f1 = __builtin_nontemporal_load((const f32x4*)(adj + rbase + 4));
        i32x4 e0 = __builtin_nontemporal_load((const i32x4*)(et + rbase));
        i32x4 e1 = __builtin_nontemporal_load((const i32x4*)(et + rbase + 4));
        s16x8 av, c;
#pragma unroll
        for (int e = 0; e < 4; ++e) { av[e] = f2bf(f0[e]); c[e] = (short)e0[e]; }
#pragma unroll
        for (int e = 0; e < 4; ++e) { av[4 + e] = f2bf(f1[e]); c[4 + e] = (short)e1[e]; }
        a[nt] = av; cd[nt] = c;
      }
#pragma unroll
      for (int r = 0; r < 8; ++r) {
        const short* bp = xwfrag + ((size_t)((r * 128 + gm) * 8 + wc * 4)) * 512 + lane * 8;
        s16x8 b[4];
#pragma unroll
        for (int t = 0; t < 4; ++t) b[t] = *(const s16x8*)(bp + t * 512);
#pragma unroll
        for (int nt = 0; nt < 4; ++nt) {
          s16x8 mfr;
#pragma unroll
          for (int e = 0; e < 8; ++e) mfr[e] = (cd[nt][e] == (short)r) ? a[nt][e] : (short)0;
#pragma unroll
          for (int t = 0; t < 4; ++t)
            acc[nt][t] = mfma16(mfr, b[t], acc[nt][t]);
        }
      }
    }
  }

  // epilogue: lane-contiguous f32x4 stores — wave instr = 1KB contiguous
  float* tile = partial + ((size_t)kc * 32 + rowblk) * 16384;
#pragma unroll
  for (int nt = 0; nt < 4; ++nt)
#pragma unroll
    for (int t = 0; t < 4; ++t)
      __builtin_nontemporal_store(
          acc[nt][t], (f32x4*)(tile + (size_t)(((w * 4 + nt) * 4 + t) * 256 + lane * 4)));
}

// ---------------------------------------------------------------------------
// K4: out = LN( hacc + sum_kc partial[kc] ) (+ReLU).
// Wave handles 4 consecutive rows (one stored quad); lane holds 2 cols x 4 rows.
// ---------------------------------------------------------------------------
__global__ void reduce_ln(const float* __restrict__ partial, int KC,
                          const float* __restrict__ hacc,
                          const float* __restrict__ gamma, const float* __restrict__ beta,
                          float* __restrict__ out, int relu) {
  int lane = threadIdx.x & 63;
  int g = blockIdx.x * 4 + (threadIdx.x >> 6);   // row-quad id, 0..1023
  int rowblk = g >> 5;
  int qin = g & 31;
  int wr = qin >> 4, nt = (qin >> 2) & 3, l4 = qin & 3;
  int rowbase = rowblk * 128 + wr * 64 + nt * 16 + l4 * 4;

  int c0 = lane, c1 = lane + 64;
  f32x4 v0, v1;
#pragma unroll
  for (int j = 0; j < 4; ++j) {
    v0[j] = hacc[(size_t)(rowbase + j) * 128 + c0];
    v1[j] = hacc[(size_t)(rowbase + j) * 128 + c1];
  }
  int t = (lane >> 4) & 3;
  size_t off0 = (size_t)(((wr * 2 + 0) * 4 + nt) * 4 + t) * 256 + (l4 * 16 + (lane & 15)) * 4;
  size_t off1 = (size_t)(((wr * 2 + 1) * 4 + nt) * 4 + t) * 256 + (l4 * 16 + (lane & 15)) * 4;
  for (int kc = 0; kc < KC; ++kc) {
    const float* tile = partial + ((size_t)kc * 32 + rowblk) * 16384;
    f32x4 p0 = *(const f32x4*)(tile + off0);
    f32x4 p1 = *(const f32x4*)(tile + off1);
#pragma unroll
    for (int j = 0; j < 4; ++j) { v0[j] += p0[j]; v1[j] += p1[j]; }
  }

  f32x4 s, sq;
#pragma unroll
  for (int j = 0; j < 4; ++j) {
    s[j]  = v0[j] + v1[j];
    sq[j] = v0[j] * v0[j] + v1[j] * v1[j];
  }
#pragma unroll
  for (int off = 32; off; off >>= 1) {
#pragma unroll
    for (int j = 0; j < 4; ++j) {
      s[j]  += __shfl_xor(s[j],  off);
      sq[j] += __shfl_xor(sq[j], off);
    }
  }
  float g0 = gamma[c0], g1 = gamma[c1], b0 = beta[c0], b1 = beta[c1];
#pragma unroll
  for (int j = 0; j < 4; ++j) {
    float mu  = s[j] * (1.f / 128.f);
    float var = sq[j] * (1.f / 128.f) - mu * mu;
    float inv = rsqrtf(var + 1e-5f);
    float y0 = (v0[j] - mu) * inv * g0 + b0;
    float y1 = (v1[j] - mu) * inv * g1 + b1;
    if (relu) { y0 = fmaxf(y0, 0.f); y1 = fmaxf(y1, 0.f); }
    out[(size_t)(rowbase + j) * 128 + c0] = y0;
    out[(size_t)(rowbase + j) * 128 + c1] = y1;
  }
}

// ---------------------------------------------------------------------------
extern "C" void kernel_launch(void* const* d_in, const int* in_sizes, int n_in,
                              void* d_out, int out_size, void* d_ws, size_t ws_size,
                              hipStream_t stream) {
  const float* x      = (const float*)d_in[0];
  const float* adj    = (const float*)d_in[1];
  const int*   et     = (const int*)d_in[2];
  const float* bases1 = (const float*)d_in[3];
  const float* wts1   = (const float*)d_in[4];
  const float* wself1 = (const float*)d_in[5];
  const float* bself1 = (const float*)d_in[6];
  const float* bases2 = (const float*)d_in[7];
  const float* wts2   = (const float*)d_in[8];
  const float* wself2 = (const float*)d_in[9];
  const float* bself2 = (const float*)d_in[10];
  const float* gamma1 = (const float*)d_in[11];
  const float* beta1  = (const float*)d_in[12];
  const float* gamma2 = (const float*)d_in[13];
  const float* beta2  = (const float*)d_in[14];

  char* ws = (char*)d_ws;
  const size_t BASE = 589824ull + 8388608ull + 2097152ull + 2097152ull; // 13,172,736
  short* wfrag  = (short*)(ws);
  short* xwfrag = (short*)(ws + 589824);
  float* hacc   = (float*)(ws + 589824 + 8388608);
  float* h1     = (float*)(ws + 589824 + 8388608 + 2097152);

  // tier selection: partials (KC * 2 MiB) after BASE; packed buffers after that
  const size_t PACKSZ = 33554432ull + 8388608ull;   // adjb + etp
  int KC = 0; bool packed = false;
  if (ws_size >= BASE + 32ull * 2097152ull + PACKSZ) { KC = 32; packed = true; }
  if (!KC) {
    const int utiers[5] = {16, 8, 4, 2, 1};
    for (int i = 0; i < 5 && !KC; ++i)
      if (ws_size >= BASE + (size_t)utiers[i] * 2097152ull) KC = utiers[i];
    if (!KC) KC = 1;
  }
  float*    partial = (float*)(ws + BASE);
  short*    adjb    = (short*)(ws + BASE + (size_t)KC * 2097152ull);
  unsigned* etp     = (unsigned*)(ws + BASE + (size_t)KC * 2097152ull + 33554432ull);
  int msteps = 128 / KC;

  prep_w<<<144, 256, 0, stream>>>(bases1, wts1, wself1, bases2, wts2, wself2, wfrag);
  if (packed)
    pack_kernel<<<8192, 256, 0, stream>>>(adj, et, adjb, etp);

  dim3 agrid(KC, 32);

  // layer 1
  xw_gemm<<<288, 256, 0, stream>>>(x, wfrag, xwfrag, hacc, bself1);
  if (packed)
    agg_kernel<true ><<<agrid, 256, 0, stream>>>(adj, et, adjb, etp, xwfrag, partial, msteps);
  else
    agg_kernel<false><<<agrid, 256, 0, stream>>>(adj, et, adjb, etp, xwfrag, partial, msteps);
  reduce_ln<<<256, 256, 0, stream>>>(partial, KC, hacc, gamma1, beta1, h1, 1);

  // layer 2
  xw_gemm<<<288, 256, 0, stream>>>(h1, wfrag + 147456, xwfrag, hacc, bself2);
  if (packed)
    agg_kernel<true ><<<agrid, 256, 0, stream>>>(adj, et, adjb, etp, xwfrag, partial, msteps);
  else
    agg_kernel<false><<<agrid, 256, 0, stream>>>(adj, et, adjb, etp, xwfrag, partial, msteps);
  reduce_ln<<<256, 256, 0, stream>>>(partial, KC, hacc, gamma2, beta2, (float*)d_out, 0);
}

// Round 6
// 219.513 us; speedup vs baseline: 3.7721x; 1.2202x over previous
//
#include <hip/hip_runtime.h>
#include <hip/hip_bf16.h>

// RGCN: N=4096, D=128, R=8, B=8, two layers + LN(+ReLU).
// R6: wave = 32 rows x 128 cols (no duplicated masking), free register
// budget (launch_bounds(256) only), immediate-offset addressing.
// Traffic layout from R4: packed bf16 adj + nibble et, lane-contiguous
// nontemporal partial stores, fused reduce+LN.

#define NN 4096
#define DD 128

typedef __attribute__((ext_vector_type(8))) short  s16x8;   // storage for 8 bf16
typedef __attribute__((ext_vector_type(8))) __bf16 bf16v8;  // MFMA operand type
typedef __attribute__((ext_vector_type(4))) float  f32x4;
typedef __attribute__((ext_vector_type(4))) int    i32x4;

__device__ inline short f2bf(float f) {            // f32 -> bf16 bits, RNE
  union { float f; unsigned u; } v; v.f = f;
  unsigned r = (v.u + 0x7FFFu + ((v.u >> 16) & 1u)) >> 16;
  return (short)r;
}

__device__ inline f32x4 mfma16(s16x8 a, s16x8 b, f32x4 c) {
  return __builtin_amdgcn_mfma_f32_16x16x32_bf16(
      __builtin_bit_cast(bf16v8, a), __builtin_bit_cast(bf16v8, b), c, 0, 0, 0);
}

// ---------------------------------------------------------------------------
// K0: pack adj (f32 -> bf16) and edge_type (i32 -> nibbles, 8/u32).
// etp words permuted within each 16-u32 group ((ms,l4) -> (l4,ms)) so agg
// lane l4 loads its 4 ms-words as one contiguous i32x4.
// ---------------------------------------------------------------------------
__global__ void pack_kernel(const float* __restrict__ adj, const int* __restrict__ et,
                            short* __restrict__ adjb, unsigned* __restrict__ etp) {
  int g = blockIdx.x * 256 + threadIdx.x;     // linear u32 index, 0 .. 2M-1
  size_t base = (size_t)g * 8;
  f32x4 f0 = *(const f32x4*)(adj + base);
  f32x4 f1 = *(const f32x4*)(adj + base + 4);
  i32x4 e0 = *(const i32x4*)(et + base);
  i32x4 e1 = *(const i32x4*)(et + base + 4);
  short v[8];
#pragma unroll
  for (int e = 0; e < 4; ++e) v[e] = f2bf(f0[e]);
#pragma unroll
  for (int e = 0; e < 4; ++e) v[4 + e] = f2bf(f1[e]);
  unsigned pk = 0;
#pragma unroll
  for (int e = 0; e < 4; ++e) pk |= ((unsigned)e0[e] & 7u) << (4 * e);
#pragma unroll
  for (int e = 0; e < 4; ++e) pk |= ((unsigned)e1[e] & 7u) << (4 * (e + 4));
  *(s16x8*)(adjb + base) = *(s16x8*)v;
  int m8 = g & 511, row = g >> 9;
  int np = (m8 & ~15) | ((m8 & 3) << 2) | ((m8 >> 2) & 3);
  etp[(size_t)row * 512 + np] = pk;
}

// ---------------------------------------------------------------------------
// K1: w_r = sum_b weights[r,b]*bases[b] (r==8 -> W_self), pre-fragmented
// B-frags: [layer][r(9)][s(4)][t(8)][lane(64)][e(8)],
// elem = w[i = 32s+8*(l>>4)+e][o = 16t+(l&15)].
// ---------------------------------------------------------------------------
__global__ void prep_w(const float* __restrict__ b1, const float* __restrict__ w1,
                       const float* __restrict__ ws1,
                       const float* __restrict__ b2, const float* __restrict__ w2,
                       const float* __restrict__ ws2,
                       short* __restrict__ wfrag) {
  int tid = blockIdx.x * 256 + threadIdx.x;   // 0..36863 (2 layers x 18432)
  int layer = (tid >= 18432);
  int t0 = tid - layer * 18432;
  int lane = t0 & 63;
  int t = (t0 >> 6) & 7;
  int s = (t0 >> 9) & 3;
  int r = t0 >> 11;                            // 0..8
  const float* bases = layer ? b2 : b1;
  const float* wts   = layer ? w2 : w1;
  const float* wself = layer ? ws2 : ws1;
  int o  = t * 16 + (lane & 15);
  int i0 = s * 32 + 8 * (lane >> 4);
  short v[8];
#pragma unroll
  for (int e = 0; e < 8; ++e) {
    int i = i0 + e;
    float a;
    if (r < 8) {
      a = 0.f;
#pragma unroll
      for (int b = 0; b < 8; ++b)
        a += wts[r * 8 + b] * bases[((size_t)b * 128 + i) * 128 + o];
    } else {
      a = wself[(size_t)i * 128 + o];
    }
    v[e] = f2bf(a);
  }
  *(s16x8*)(wfrag + (size_t)tid * 8) = *(s16x8*)v;
}

// ---------------------------------------------------------------------------
// K2: xw_r = xin @ w_r for r=0..7 -> xwfrag (agg B-frag layout)
//     [r][mstep(128)][t(8)][lane(64)][e(8)]
//     r==8: hacc = xin @ W_self + bias (f32; base term for reduce)
// ---------------------------------------------------------------------------
__global__ void xw_gemm(const float* __restrict__ xin, const short* __restrict__ wfrag,
                        short* __restrict__ xwfrag, float* __restrict__ hacc,
                        const float* __restrict__ bias) {
  __shared__ short lds[4][32 * 128];
  int w = threadIdx.x >> 6, lane = threadIdx.x & 63;
  int widx = blockIdx.x * 4 + w;   // 0..1151
  int m = widx & 127;              // 32-row tile
  int r = widx >> 7;               // 0..8
  int l15 = lane & 15, l4 = lane >> 4;

  f32x4 acc[2][8] = {};

#pragma unroll
  for (int s = 0; s < 4; ++s) {
    s16x8 A[2];
#pragma unroll
    for (int nt = 0; nt < 2; ++nt) {
      const float* xp = xin + (size_t)(m * 32 + nt * 16 + l15) * 128 + s * 32 + 8 * l4;
      f32x4 f0 = *(const f32x4*)xp;
      f32x4 f1 = *(const f32x4*)(xp + 4);
      s16x8 av;
#pragma unroll
      for (int e = 0; e < 4; ++e) av[e] = f2bf(f0[e]);
#pragma unroll
      for (int e = 0; e < 4; ++e) av[4 + e] = f2bf(f1[e]);
      A[nt] = av;
    }
    const short* bp = wfrag + ((size_t)(r * 4 + s) * 8) * 512 + lane * 8;
#pragma unroll
    for (int t = 0; t < 8; ++t) {
      s16x8 B = *(const s16x8*)(bp + t * 512);
      acc[0][t] = mfma16(A[0], B, acc[0][t]);
      acc[1][t] = mfma16(A[1], B, acc[1][t]);
    }
  }

  if (r == 8) {
#pragma unroll
    for (int nt = 0; nt < 2; ++nt)
#pragma unroll
      for (int t = 0; t < 8; ++t)
#pragma unroll
        for (int j = 0; j < 4; ++j) {
          int row = m * 32 + nt * 16 + 4 * l4 + j;
          int col = t * 16 + l15;
          hacc[(size_t)row * 128 + col] = acc[nt][t][j] + bias[col];
        }
  } else {
#pragma unroll
    for (int nt = 0; nt < 2; ++nt)
#pragma unroll
      for (int t = 0; t < 8; ++t)
#pragma unroll
        for (int j = 0; j < 4; ++j)
          lds[w][(nt * 16 + 4 * l4 + j) * 128 + t * 16 + l15] = f2bf(acc[nt][t][j]);
    __syncthreads();
#pragma unroll
    for (int t = 0; t < 8; ++t) {
      short v[8];
#pragma unroll
      for (int e = 0; e < 8; ++e) v[e] = lds[w][(8 * l4 + e) * 128 + t * 16 + l15];
      *(s16x8*)(xwfrag + ((size_t)(r * 128 + m) * 8 + t) * 512 + lane * 8) = *(s16x8*)v;
    }
  }
}

// ---------------------------------------------------------------------------
// K3: partial[kc][rowblk] = sum_r (adj .* (et==r))[rows, kchunk] @ xw_r[kchunk]
// Grid dim3(KC,32). Block = 4 waves; wave = 32 rows x 128 cols (rows disjoint
// across waves -> no duplicated mask work). Per r: 8 independent b-loads,
// 2 masked A-frags, 16 MFMA. All inner offsets are compile-time immediates.
// ---------------------------------------------------------------------------
template <bool PACKED>
__launch_bounds__(256)
__global__ void agg_kernel(const float* __restrict__ adj, const int* __restrict__ et,
                           const short* __restrict__ adjb, const unsigned* __restrict__ etp,
                           const short* __restrict__ xwfrag, float* __restrict__ partial,
                           int msteps) {
  int w = threadIdx.x >> 6, lane = threadIdx.x & 63;
  int kc = blockIdx.x;
  int rowblk = blockIdx.y;
  int rowbase = rowblk * 128 + w * 32;
  int l15 = lane & 15, l4 = lane >> 4;

  f32x4 acc[2][8] = {};

  if constexpr (PACKED) {
    const short* ap0; const short* ap1;
    i32x4 V[2];
    {
      size_t r0 = (size_t)(rowbase + l15);
      size_t r1 = (size_t)(rowbase + 16 + l15);
      ap0 = adjb + r0 * 4096 + kc * 128 + 8 * l4;
      ap1 = adjb + r1 * 4096 + kc * 128 + 8 * l4;
      V[0] = __builtin_nontemporal_load((const i32x4*)(etp + r0 * 512 + kc * 16 + l4 * 4));
      V[1] = __builtin_nontemporal_load((const i32x4*)(etp + r1 * 512 + kc * 16 + l4 * 4));
    }
    // A prefetch pipeline (1-deep)
    s16x8 A[2][2];
    A[0][0] = __builtin_nontemporal_load((const s16x8*)ap0);
    A[0][1] = __builtin_nontemporal_load((const s16x8*)ap1);

    const short* bbase = xwfrag + ((size_t)kc * 4 * 8) * 512 + lane * 8;

#pragma unroll
    for (int ms = 0; ms < 4; ++ms) {
      int cur = ms & 1, nxt = cur ^ 1;
      if (ms < 3) {
        A[nxt][0] = __builtin_nontemporal_load((const s16x8*)(ap0 + (ms + 1) * 32));
        A[nxt][1] = __builtin_nontemporal_load((const s16x8*)(ap1 + (ms + 1) * 32));
      }
      // nibble expansion, reused by all 8 relations
      s16x8 cd[2];
#pragma unroll
      for (int nt = 0; nt < 2; ++nt) {
        unsigned pk = (unsigned)V[nt][ms];
        s16x8 c;
#pragma unroll
        for (int e = 0; e < 8; ++e) c[e] = (short)((pk >> (4 * e)) & 7u);
        cd[nt] = c;
      }
#pragma unroll
      for (int r = 0; r < 8; ++r) {
        // offsets: ((r*128 + ms)*8 + t)*512 shorts from bbase (compile-time)
        const short* bp = bbase + ((size_t)r * 128 + ms) * 8 * 512;
        s16x8 b[8];
#pragma unroll
        for (int t = 0; t < 8; ++t) b[t] = *(const s16x8*)(bp + t * 512);
        s16x8 mfr[2];
#pragma unroll
        for (int nt = 0; nt < 2; ++nt)
#pragma unroll
          for (int e = 0; e < 8; ++e)
            mfr[nt][e] = (cd[nt][e] == (short)r) ? A[cur][nt][e] : (short)0;
#pragma unroll
        for (int t = 0; t < 8; ++t) {
          acc[0][t] = mfma16(mfr[0], b[t], acc[0][t]);
          acc[1][t] = mfma16(mfr[1], b[t], acc[1][t]);
        }
      }
    }
  } else {
    for (int ms = 0; ms < msteps; ++ms) {
      int gm = kc * msteps + ms;
      s16x8 a[2]; s16x8 cd[2];
#pragma unroll
      for (int nt = 0; nt < 2; ++nt) {
        size_t rbase = (size_t)(rowbase + nt * 16 + l15) * 4096 + gm * 32 + 8 * l4;
        f32x4 f0 = __builtin_nontemporal_load((const f32x4*)(adj + rbase));
        f32x4 f1 = __builtin_nontemporal_load((const f32x4*)(adj + rbase + 4));
        i32x4 e0 = __builtin_nontemporal_load((const i32x4*)(et + rbase));
        i32x4 e1 = __builtin_nontemporal_load((const i32x4*)(et + rbase + 4));
        s16x8 av, c;
#pragma unroll
        for (int e = 0; e < 4; ++e) { av[e] = f2bf(f0[e]); c[e] = (short)e0[e]; }
#pragma unroll
        for (int e = 0; e < 4; ++e) { av[4 + e] = f2bf(f1[e]); c[4 + e] = (short)e1[e]; }
        a[nt] = av; cd[nt] = c;
      }
#pragma unroll
      for (int r = 0; r < 8; ++r) {
        const short* bp = xwfrag + ((size_t)(r * 128 + gm) * 8) * 512 + lane * 8;
        s16x8 b[8];
#pragma unroll
        for (int t = 0; t < 8; ++t) b[t] = *(const s16x8*)(bp + t * 512);
        s16x8 mfr[2];
#pragma unroll
        for (int nt = 0; nt < 2; ++nt)
#pragma unroll
          for (int e = 0; e < 8; ++e)
            mfr[nt][e] = (cd[nt][e] == (short)r) ? a[nt][e] : (short)0;
#pragma unroll
        for (int t = 0; t < 8; ++t) {
          acc[0][t] = mfma16(mfr[0], b[t], acc[0][t]);
          acc[1][t] = mfma16(mfr[1], b[t], acc[1][t]);
        }
      }
    }
  }

  // epilogue: lane-contiguous f32x4 stores; wave store instr = 1KB contiguous
  float* tile = partial + ((size_t)kc * 32 + rowblk) * 16384;
#pragma unroll
  for (int nt = 0; nt < 2; ++nt)
#pragma unroll
    for (int t = 0; t < 8; ++t)
      __builtin_nontemporal_store(
          acc[nt][t], (f32x4*)(tile + (size_t)((((w * 2 + nt) * 8 + t) * 256) + lane * 4)));
}

// ---------------------------------------------------------------------------
// K4: out = LN( hacc + sum_kc partial[kc] ) (+ReLU).
// One wave per 4-row quad; lane holds 2 cols x 4 rows. Tile layout:
// value(rl,c) at ((w*2+nt)*8 + t)*256 + (l4*16+li)*4 + j,
//   rl = w*32+nt*16+4*l4+j, c = t*16+li.
// ---------------------------------------------------------------------------
__global__ void reduce_ln(const float* __restrict__ partial, int KC,
                          const float* __restrict__ hacc,
                          const float* __restrict__ gamma, const float* __restrict__ beta,
                          float* __restrict__ out, int relu) {
  int lane = threadIdx.x & 63;
  int g = blockIdx.x * 4 + (threadIdx.x >> 6);   // row-quad id, 0..1023
  int rowblk = g >> 5;
  int q = g & 31;                                 // quad within 128-row block
  int w  = q >> 3;
  int nt = (q >> 2) & 1;
  int l4g = q & 3;
  int rowbase = rowblk * 128 + q * 4;

  int c0 = lane, c1 = lane + 64;
  int t0 = lane >> 4, li = lane & 15;
  f32x4 v0, v1;
#pragma unroll
  for (int j = 0; j < 4; ++j) {
    v0[j] = hacc[(size_t)(rowbase + j) * 128 + c0];
    v1[j] = hacc[(size_t)(rowbase + j) * 128 + c1];
  }
  size_t off0 = (size_t)(((w * 2 + nt) * 8 + t0) * 256) + (l4g * 16 + li) * 4;
  size_t off1 = (size_t)(((w * 2 + nt) * 8 + t0 + 4) * 256) + (l4g * 16 + li) * 4;
  for (int kc = 0; kc < KC; ++kc) {
    const float* tile = partial + ((size_t)kc * 32 + rowblk) * 16384;
    f32x4 p0 = *(const f32x4*)(tile + off0);
    f32x4 p1 = *(const f32x4*)(tile + off1);
#pragma unroll
    for (int j = 0; j < 4; ++j) { v0[j] += p0[j]; v1[j] += p1[j]; }
  }

  f32x4 s, sq;
#pragma unroll
  for (int j = 0; j < 4; ++j) {
    s[j]  = v0[j] + v1[j];
    sq[j] = v0[j] * v0[j] + v1[j] * v1[j];
  }
#pragma unroll
  for (int off = 32; off; off >>= 1) {
#pragma unroll
    for (int j = 0; j < 4; ++j) {
      s[j]  += __shfl_xor(s[j],  off);
      sq[j] += __shfl_xor(sq[j], off);
    }
  }
  float g0 = gamma[c0], g1 = gamma[c1], b0 = beta[c0], b1 = beta[c1];
#pragma unroll
  for (int j = 0; j < 4; ++j) {
    float mu  = s[j] * (1.f / 128.f);
    float var = sq[j] * (1.f / 128.f) - mu * mu;
    float inv = rsqrtf(var + 1e-5f);
    float y0 = (v0[j] - mu) * inv * g0 + b0;
    float y1 = (v1[j] - mu) * inv * g1 + b1;
    if (relu) { y0 = fmaxf(y0, 0.f); y1 = fmaxf(y1, 0.f); }
    out[(size_t)(rowbase + j) * 128 + c0] = y0;
    out[(size_t)(rowbase + j) * 128 + c1] = y1;
  }
}

// ---------------------------------------------------------------------------
extern "C" void kernel_launch(void* const* d_in, const int* in_sizes, int n_in,
                              void* d_out, int out_size, void* d_ws, size_t ws_size,
                              hipStream_t stream) {
  const float* x      = (const float*)d_in[0];
  const float* adj    = (const float*)d_in[1];
  const int*   et     = (const int*)d_in[2];
  const float* bases1 = (const float*)d_in[3];
  const float* wts1   = (const float*)d_in[4];
  const float* wself1 = (const float*)d_in[5];
  const float* bself1 = (const float*)d_in[6];
  const float* bases2 = (const float*)d_in[7];
  const float* wts2   = (const float*)d_in[8];
  const float* wself2 = (const float*)d_in[9];
  const float* bself2 = (const float*)d_in[10];
  const float* gamma1 = (const float*)d_in[11];
  const float* beta1  = (const float*)d_in[12];
  const float* gamma2 = (const float*)d_in[13];
  const float* beta2  = (const float*)d_in[14];

  char* ws = (char*)d_ws;
  const size_t BASE = 589824ull + 8388608ull + 2097152ull + 2097152ull; // 13,172,736
  short* wfrag  = (short*)(ws);
  short* xwfrag = (short*)(ws + 589824);
  float* hacc   = (float*)(ws + 589824 + 8388608);
  float* h1     = (float*)(ws + 589824 + 8388608 + 2097152);

  // tier selection: partials (KC * 2 MiB) after BASE; packed buffers after that
  const size_t PACKSZ = 33554432ull + 8388608ull;   // adjb + etp
  int KC = 0; bool packed = false;
  if (ws_size >= BASE + 32ull * 2097152ull + PACKSZ) { KC = 32; packed = true; }
  if (!KC) {
    const int utiers[5] = {16, 8, 4, 2, 1};
    for (int i = 0; i < 5 && !KC; ++i)
      if (ws_size >= BASE + (size_t)utiers[i] * 2097152ull) KC = utiers[i];
    if (!KC) KC = 1;
  }
  float*    partial = (float*)(ws + BASE);
  short*    adjb    = (short*)(ws + BASE + (size_t)KC * 2097152ull);
  unsigned* etp     = (unsigned*)(ws + BASE + (size_t)KC * 2097152ull + 33554432ull);
  int msteps = 128 / KC;

  prep_w<<<144, 256, 0, stream>>>(bases1, wts1, wself1, bases2, wts2, wself2, wfrag);
  if (packed)
    pack_kernel<<<8192, 256, 0, stream>>>(adj, et, adjb, etp);

  dim3 agrid(KC, 32);

  // layer 1
  xw_gemm<<<288, 256, 0, stream>>>(x, wfrag, xwfrag, hacc, bself1);
  if (packed)
    agg_kernel<true ><<<agrid, 256, 0, stream>>>(adj, et, adjb, etp, xwfrag, partial, msteps);
  else
    agg_kernel<false><<<agrid, 256, 0, stream>>>(adj, et, adjb, etp, xwfrag, partial, msteps);
  reduce_ln<<<256, 256, 0, stream>>>(partial, KC, hacc, gamma1, beta1, h1, 1);

  // layer 2
  xw_gemm<<<288, 256, 0, stream>>>(h1, wfrag + 147456, xwfrag, hacc, bself2);
  if (packed)
    agg_kernel<true ><<<agrid, 256, 0, stream>>>(adj, et, adjb, etp, xwfrag, partial, msteps);
  else
    agg_kernel<false><<<agrid, 256, 0, stream>>>(adj, et, adjb, etp, xwfrag, partial, msteps);
  reduce_ln<<<256, 256, 0, stream>>>(partial, KC, hacc, gamma2, beta2, (float*)d_out, 0);
}

// Round 7
// 203.951 us; speedup vs baseline: 4.0599x; 1.0763x over previous
//
#include <hip/hip_runtime.h>
#include <hip/hip_bf16.h>

// RGCN: N=4096, D=128, R=8, B=8, two layers + LN(+ReLU).
// R7: occupancy fix — wave tile 32x64 (acc=32 regs), 512-thread blocks,
// __launch_bounds__(512,4) -> 16 waves/CU (was 8). KC=16 halves partial
// traffic. Packed bf16 adj + nibble et, lane-contiguous nontemporal stores.

#define NN 4096
#define DD 128

typedef __attribute__((ext_vector_type(8))) short  s16x8;   // storage for 8 bf16
typedef __attribute__((ext_vector_type(8))) __bf16 bf16v8;  // MFMA operand type
typedef __attribute__((ext_vector_type(4))) float  f32x4;
typedef __attribute__((ext_vector_type(4))) int    i32x4;

__device__ inline short f2bf(float f) {            // f32 -> bf16 bits, RNE
  union { float f; unsigned u; } v; v.f = f;
  unsigned r = (v.u + 0x7FFFu + ((v.u >> 16) & 1u)) >> 16;
  return (short)r;
}

__device__ inline f32x4 mfma16(s16x8 a, s16x8 b, f32x4 c) {
  return __builtin_amdgcn_mfma_f32_16x16x32_bf16(
      __builtin_bit_cast(bf16v8, a), __builtin_bit_cast(bf16v8, b), c, 0, 0, 0);
}

// ---------------------------------------------------------------------------
// K0: pack adj (f32 -> bf16) and edge_type (i32 -> nibbles, 8/u32).
// etp words permuted within each 16-u32 group ((ms,l4) -> (l4,ms)) so agg
// lane l4 can load 4 consecutive ms-words as one i32x4.
// ---------------------------------------------------------------------------
__global__ void pack_kernel(const float* __restrict__ adj, const int* __restrict__ et,
                            short* __restrict__ adjb, unsigned* __restrict__ etp) {
  int g = blockIdx.x * 256 + threadIdx.x;     // linear u32 index, 0 .. 2M-1
  size_t base = (size_t)g * 8;
  f32x4 f0 = *(const f32x4*)(adj + base);
  f32x4 f1 = *(const f32x4*)(adj + base + 4);
  i32x4 e0 = *(const i32x4*)(et + base);
  i32x4 e1 = *(const i32x4*)(et + base + 4);
  short v[8];
#pragma unroll
  for (int e = 0; e < 4; ++e) v[e] = f2bf(f0[e]);
#pragma unroll
  for (int e = 0; e < 4; ++e) v[4 + e] = f2bf(f1[e]);
  unsigned pk = 0;
#pragma unroll
  for (int e = 0; e < 4; ++e) pk |= ((unsigned)e0[e] & 7u) << (4 * e);
#pragma unroll
  for (int e = 0; e < 4; ++e) pk |= ((unsigned)e1[e] & 7u) << (4 * (e + 4));
  *(s16x8*)(adjb + base) = *(s16x8*)v;
  int m8 = g & 511, row = g >> 9;
  int np = (m8 & ~15) | ((m8 & 3) << 2) | ((m8 >> 2) & 3);
  etp[(size_t)row * 512 + np] = pk;
}

// ---------------------------------------------------------------------------
// K1: w_r = sum_b weights[r,b]*bases[b] (r==8 -> W_self), pre-fragmented
// B-frags: [layer][r(9)][s(4)][t(8)][lane(64)][e(8)],
// elem = w[i = 32s+8*(l>>4)+e][o = 16t+(l&15)].
// ---------------------------------------------------------------------------
__global__ void prep_w(const float* __restrict__ b1, const float* __restrict__ w1,
                       const float* __restrict__ ws1,
                       const float* __restrict__ b2, const float* __restrict__ w2,
                       const float* __restrict__ ws2,
                       short* __restrict__ wfrag) {
  int tid = blockIdx.x * 256 + threadIdx.x;   // 0..36863 (2 layers x 18432)
  int layer = (tid >= 18432);
  int t0 = tid - layer * 18432;
  int lane = t0 & 63;
  int t = (t0 >> 6) & 7;
  int s = (t0 >> 9) & 3;
  int r = t0 >> 11;                            // 0..8
  const float* bases = layer ? b2 : b1;
  const float* wts   = layer ? w2 : w1;
  const float* wself = layer ? ws2 : ws1;
  int o  = t * 16 + (lane & 15);
  int i0 = s * 32 + 8 * (lane >> 4);
  short v[8];
#pragma unroll
  for (int e = 0; e < 8; ++e) {
    int i = i0 + e;
    float a;
    if (r < 8) {
      a = 0.f;
#pragma unroll
      for (int b = 0; b < 8; ++b)
        a += wts[r * 8 + b] * bases[((size_t)b * 128 + i) * 128 + o];
    } else {
      a = wself[(size_t)i * 128 + o];
    }
    v[e] = f2bf(a);
  }
  *(s16x8*)(wfrag + (size_t)tid * 8) = *(s16x8*)v;
}

// ---------------------------------------------------------------------------
// K2: xw_r = xin @ w_r for r=0..7 -> xwfrag (agg B-frag layout)
//     [r][mstep(128)][t(8)][lane(64)][e(8)]
//     r==8: hacc = xin @ W_self + bias (f32; base term for reduce)
// ---------------------------------------------------------------------------
__global__ void xw_gemm(const float* __restrict__ xin, const short* __restrict__ wfrag,
                        short* __restrict__ xwfrag, float* __restrict__ hacc,
                        const float* __restrict__ bias) {
  __shared__ short lds[4][32 * 128];
  int w = threadIdx.x >> 6, lane = threadIdx.x & 63;
  int widx = blockIdx.x * 4 + w;   // 0..1151
  int m = widx & 127;              // 32-row tile
  int r = widx >> 7;               // 0..8
  int l15 = lane & 15, l4 = lane >> 4;

  f32x4 acc[2][8] = {};

#pragma unroll
  for (int s = 0; s < 4; ++s) {
    s16x8 A[2];
#pragma unroll
    for (int nt = 0; nt < 2; ++nt) {
      const float* xp = xin + (size_t)(m * 32 + nt * 16 + l15) * 128 + s * 32 + 8 * l4;
      f32x4 f0 = *(const f32x4*)xp;
      f32x4 f1 = *(const f32x4*)(xp + 4);
      s16x8 av;
#pragma unroll
      for (int e = 0; e < 4; ++e) av[e] = f2bf(f0[e]);
#pragma unroll
      for (int e = 0; e < 4; ++e) av[4 + e] = f2bf(f1[e]);
      A[nt] = av;
    }
    const short* bp = wfrag + ((size_t)(r * 4 + s) * 8) * 512 + lane * 8;
#pragma unroll
    for (int t = 0; t < 8; ++t) {
      s16x8 B = *(const s16x8*)(bp + t * 512);
      acc[0][t] = mfma16(A[0], B, acc[0][t]);
      acc[1][t] = mfma16(A[1], B, acc[1][t]);
    }
  }

  if (r == 8) {
#pragma unroll
    for (int nt = 0; nt < 2; ++nt)
#pragma unroll
      for (int t = 0; t < 8; ++t)
#pragma unroll
        for (int j = 0; j < 4; ++j) {
          int row = m * 32 + nt * 16 + 4 * l4 + j;
          int col = t * 16 + l15;
          hacc[(size_t)row * 128 + col] = acc[nt][t][j] + bias[col];
        }
  } else {
#pragma unroll
    for (int nt = 0; nt < 2; ++nt)
#pragma unroll
      for (int t = 0; t < 8; ++t)
#pragma unroll
        for (int j = 0; j < 4; ++j)
          lds[w][(nt * 16 + 4 * l4 + j) * 128 + t * 16 + l15] = f2bf(acc[nt][t][j]);
    __syncthreads();
#pragma unroll
    for (int t = 0; t < 8; ++t) {
      short v[8];
#pragma unroll
      for (int e = 0; e < 8; ++e) v[e] = lds[w][(8 * l4 + e) * 128 + t * 16 + l15];
      *(s16x8*)(xwfrag + ((size_t)(r * 128 + m) * 8 + t) * 512 + lane * 8) = *(s16x8*)v;
    }
  }
}

// ---------------------------------------------------------------------------
// K3: partial[kc][rowblk] += per-relation masked adjacency @ xw_r, k-chunked.
// Grid dim3(KC,32), block = 512 threads = 8 waves: w = wr*2+wc,
// wave tile = 32 rows (wr) x 64 cols (wc). acc[2][4] = 32 VGPR.
// A loaded once per 128x128 block (wc pair dedupes in cache); b = 4 loads/r.
// ---------------------------------------------------------------------------
template <bool PACKED>
__launch_bounds__(512, 4)
__global__ void agg_kernel(const float* __restrict__ adj, const int* __restrict__ et,
                           const short* __restrict__ adjb, const unsigned* __restrict__ etp,
                           const short* __restrict__ xwfrag, float* __restrict__ partial,
                           int msteps) {
  int w = threadIdx.x >> 6, lane = threadIdx.x & 63;
  int kc = blockIdx.x;
  int rowblk = blockIdx.y;
  int wr = w >> 1, wc = w & 1;
  int rowbase = rowblk * 128 + wr * 32;
  int l15 = lane & 15, l4 = lane >> 4;

  f32x4 acc[2][4] = {};

  if constexpr (PACKED) {
    size_t r0 = (size_t)(rowbase + l15);
    size_t r1 = (size_t)(rowbase + 16 + l15);
    const short* ap0 = adjb + r0 * 4096 + kc * 256 + 8 * l4;   // msteps=8: 256 cols/kc
    const short* ap1 = adjb + r1 * 4096 + kc * 256 + 8 * l4;
    // nibble words for this kc chunk: 8 ms-words = 2 x i32x4 per row
    i32x4 V0[2], V1[2];
#pragma unroll
    for (int h = 0; h < 2; ++h) {
      V0[h] = __builtin_nontemporal_load((const i32x4*)(etp + r0 * 512 + kc * 32 + h * 16 + l4 * 4));
      V1[h] = __builtin_nontemporal_load((const i32x4*)(etp + r1 * 512 + kc * 32 + h * 16 + l4 * 4));
    }
    // A prefetch pipeline (1-deep)
    s16x8 A[2][2];
    A[0][0] = __builtin_nontemporal_load((const s16x8*)ap0);
    A[0][1] = __builtin_nontemporal_load((const s16x8*)ap1);

    const short* bbase = xwfrag + ((size_t)(kc * 8) * 8 + wc * 4) * 512 + lane * 8;

#pragma unroll
    for (int ms = 0; ms < 8; ++ms) {
      int cur = ms & 1, nxt = cur ^ 1;
      if (ms < 7) {
        A[nxt][0] = __builtin_nontemporal_load((const s16x8*)(ap0 + (ms + 1) * 32));
        A[nxt][1] = __builtin_nontemporal_load((const s16x8*)(ap1 + (ms + 1) * 32));
      }
      // nibble expansion, reused by all 8 relations
      unsigned pk0 = (unsigned)V0[ms >> 2][ms & 3];
      unsigned pk1 = (unsigned)V1[ms >> 2][ms & 3];
      s16x8 cd0, cd1;
#pragma unroll
      for (int e = 0; e < 8; ++e) {
        cd0[e] = (short)((pk0 >> (4 * e)) & 7u);
        cd1[e] = (short)((pk1 >> (4 * e)) & 7u);
      }
#pragma unroll
      for (int r = 0; r < 8; ++r) {
        const short* bp = bbase + ((size_t)r * 128 + ms) * 8 * 512;
        s16x8 b[4];
#pragma unroll
        for (int t = 0; t < 4; ++t) b[t] = *(const s16x8*)(bp + t * 512);
        s16x8 m0, m1;
#pragma unroll
        for (int e = 0; e < 8; ++e) {
          m0[e] = (cd0[e] == (short)r) ? A[cur][0][e] : (short)0;
          m1[e] = (cd1[e] == (short)r) ? A[cur][1][e] : (short)0;
        }
#pragma unroll
        for (int t = 0; t < 4; ++t) {
          acc[0][t] = mfma16(m0, b[t], acc[0][t]);
          acc[1][t] = mfma16(m1, b[t], acc[1][t]);
        }
      }
    }
  } else {
    for (int ms = 0; ms < msteps; ++ms) {
      int gm = kc * msteps + ms;
      s16x8 a[2]; s16x8 cd[2];
#pragma unroll
      for (int nt = 0; nt < 2; ++nt) {
        size_t rbase = (size_t)(rowbase + nt * 16 + l15) * 4096 + gm * 32 + 8 * l4;
        f32x4 f0 = __builtin_nontemporal_load((const f32x4*)(adj + rbase));
        f32x4 f1 = __builtin_nontemporal_load((const f32x4*)(adj + rbase + 4));
        i32x4 e0 = __builtin_nontemporal_load((const i32x4*)(et + rbase));
        i32x4 e1 = __builtin_nontemporal_load((const i32x4*)(et + rbase + 4));
        s16x8 av, c;
#pragma unroll
        for (int e = 0; e < 4; ++e) { av[e] = f2bf(f0[e]); c[e] = (short)e0[e]; }
#pragma unroll
        for (int e = 0; e < 4; ++e) { av[4 + e] = f2bf(f1[e]); c[4 + e] = (short)e1[e]; }
        a[nt] = av; cd[nt] = c;
      }
#pragma unroll
      for (int r = 0; r < 8; ++r) {
        const short* bp = xwfrag + ((size_t)(r * 128 + gm) * 8 + wc * 4) * 512 + lane * 8;
        s16x8 b[4];
#pragma unroll
        for (int t = 0; t < 4; ++t) b[t] = *(const s16x8*)(bp + t * 512);
        s16x8 m0, m1;
#pragma unroll
        for (int e = 0; e < 8; ++e) {
          m0[e] = (cd[0][e] == (short)r) ? a[0][e] : (short)0;
          m1[e] = (cd[1][e] == (short)r) ? a[1][e] : (short)0;
        }
#pragma unroll
        for (int t = 0; t < 4; ++t) {
          acc[0][t] = mfma16(m0, b[t], acc[0][t]);
          acc[1][t] = mfma16(m1, b[t], acc[1][t]);
        }
      }
    }
  }

  // epilogue: lane-contiguous f32x4 stores; wave store instr = 1KB contiguous
  float* tile = partial + ((size_t)kc * 32 + rowblk) * 16384;
#pragma unroll
  for (int nt = 0; nt < 2; ++nt)
#pragma unroll
    for (int t = 0; t < 4; ++t)
      __builtin_nontemporal_store(
          acc[nt][t], (f32x4*)(tile + (size_t)(((w * 2 + nt) * 4 + t) * 256 + lane * 4)));
}

// ---------------------------------------------------------------------------
// K4: out = LN( hacc + sum_kc partial[kc] ) (+ReLU).
// Tile layout inverse: value(row,col) at (((wr*2+wc)*2+nt)*4 + t)*256
//   + (l4*16+li)*4 + j, where row = wr*32+nt*16+4*l4+j, col = wc*64+t*16+li.
// One wave per 4-row quad; lane holds cols {lane, lane+64} x 4 rows.
// ---------------------------------------------------------------------------
__global__ void reduce_ln(const float* __restrict__ partial, int KC,
                          const float* __restrict__ hacc,
                          const float* __restrict__ gamma, const float* __restrict__ beta,
                          float* __restrict__ out, int relu) {
  int lane = threadIdx.x & 63;
  int g = blockIdx.x * 4 + (threadIdx.x >> 6);   // row-quad id, 0..1023
  int rowblk = g >> 5;
  int q = g & 31;                                 // quad within 128-row block
  int wr  = q >> 3;
  int nt  = (q >> 2) & 1;
  int l4g = q & 3;
  int rowbase = rowblk * 128 + q * 4;

  int c0 = lane, c1 = lane + 64;
  int t0 = lane >> 4, li = lane & 15;
  f32x4 v0, v1;
#pragma unroll
  for (int j = 0; j < 4; ++j) {
    v0[j] = hacc[(size_t)(rowbase + j) * 128 + c0];
    v1[j] = hacc[(size_t)(rowbase + j) * 128 + c1];
  }
  size_t off0 = (size_t)((((wr * 2 + 0) * 2 + nt) * 4 + t0) * 256) + (l4g * 16 + li) * 4;
  size_t off1 = (size_t)((((wr * 2 + 1) * 2 + nt) * 4 + t0) * 256) + (l4g * 16 + li) * 4;
  for (int kc = 0; kc < KC; ++kc) {
    const float* tile = partial + ((size_t)kc * 32 + rowblk) * 16384;
    f32x4 p0 = *(const f32x4*)(tile + off0);
    f32x4 p1 = *(const f32x4*)(tile + off1);
#pragma unroll
    for (int j = 0; j < 4; ++j) { v0[j] += p0[j]; v1[j] += p1[j]; }
  }

  f32x4 s, sq;
#pragma unroll
  for (int j = 0; j < 4; ++j) {
    s[j]  = v0[j] + v1[j];
    sq[j] = v0[j] * v0[j] + v1[j] * v1[j];
  }
#pragma unroll
  for (int off = 32; off; off >>= 1) {
#pragma unroll
    for (int j = 0; j < 4; ++j) {
      s[j]  += __shfl_xor(s[j],  off);
      sq[j] += __shfl_xor(sq[j], off);
    }
  }
  float g0 = gamma[c0], g1 = gamma[c1], b0 = beta[c0], b1 = beta[c1];
#pragma unroll
  for (int j = 0; j < 4; ++j) {
    float mu  = s[j] * (1.f / 128.f);
    float var = sq[j] * (1.f / 128.f) - mu * mu;
    float inv = rsqrtf(var + 1e-5f);
    float y0 = (v0[j] - mu) * inv * g0 + b0;
    float y1 = (v1[j] - mu) * inv * g1 + b1;
    if (relu) { y0 = fmaxf(y0, 0.f); y1 = fmaxf(y1, 0.f); }
    out[(size_t)(rowbase + j) * 128 + c0] = y0;
    out[(size_t)(rowbase + j) * 128 + c1] = y1;
  }
}

// ---------------------------------------------------------------------------
extern "C" void kernel_launch(void* const* d_in, const int* in_sizes, int n_in,
                              void* d_out, int out_size, void* d_ws, size_t ws_size,
                              hipStream_t stream) {
  const float* x      = (const float*)d_in[0];
  const float* adj    = (const float*)d_in[1];
  const int*   et     = (const int*)d_in[2];
  const float* bases1 = (const float*)d_in[3];
  const float* wts1   = (const float*)d_in[4];
  const float* wself1 = (const float*)d_in[5];
  const float* bself1 = (const float*)d_in[6];
  const float* bases2 = (const float*)d_in[7];
  const float* wts2   = (const float*)d_in[8];
  const float* wself2 = (const float*)d_in[9];
  const float* bself2 = (const float*)d_in[10];
  const float* gamma1 = (const float*)d_in[11];
  const float* beta1  = (const float*)d_in[12];
  const float* gamma2 = (const float*)d_in[13];
  const float* beta2  = (const float*)d_in[14];

  char* ws = (char*)d_ws;
  const size_t BASE = 589824ull + 8388608ull + 2097152ull + 2097152ull; // 13,172,736
  short* wfrag  = (short*)(ws);
  short* xwfrag = (short*)(ws + 589824);
  float* hacc   = (float*)(ws + 589824 + 8388608);
  float* h1     = (float*)(ws + 589824 + 8388608 + 2097152);

  // tier selection: partials (KC * 2 MiB) after BASE; packed buffers after that
  const size_t PACKSZ = 33554432ull + 8388608ull;   // adjb + etp
  int KC = 0; bool packed = false;
  if (ws_size >= BASE + 16ull * 2097152ull + PACKSZ) { KC = 16; packed = true; }
  if (!KC) {
    const int utiers[5] = {16, 8, 4, 2, 1};
    for (int i = 0; i < 5 && !KC; ++i)
      if (ws_size >= BASE + (size_t)utiers[i] * 2097152ull) KC = utiers[i];
    if (!KC) KC = 1;
  }
  float*    partial = (float*)(ws + BASE);
  short*    adjb    = (short*)(ws + BASE + (size_t)KC * 2097152ull);
  unsigned* etp     = (unsigned*)(ws + BASE + (size_t)KC * 2097152ull + 33554432ull);
  int msteps = 128 / KC;

  prep_w<<<144, 256, 0, stream>>>(bases1, wts1, wself1, bases2, wts2, wself2, wfrag);
  if (packed)
    pack_kernel<<<8192, 256, 0, stream>>>(adj, et, adjb, etp);

  dim3 agrid(KC, 32);

  // layer 1
  xw_gemm<<<288, 256, 0, stream>>>(x, wfrag, xwfrag, hacc, bself1);
  if (packed)
    agg_kernel<true ><<<agrid, 512, 0, stream>>>(adj, et, adjb, etp, xwfrag, partial, msteps);
  else
    agg_kernel<false><<<agrid, 512, 0, stream>>>(adj, et, adjb, etp, xwfrag, partial, msteps);
  reduce_ln<<<256, 256, 0, stream>>>(partial, KC, hacc, gamma1, beta1, h1, 1);

  // layer 2
  xw_gemm<<<288, 256, 0, stream>>>(h1, wfrag + 147456, xwfrag, hacc, bself2);
  if (packed)
    agg_kernel<true ><<<agrid, 512, 0, stream>>>(adj, et, adjb, etp, xwfrag, partial, msteps);
  else
    agg_kernel<false><<<agrid, 512, 0, stream>>>(adj, et, adjb, etp, xwfrag, partial, msteps);
  reduce_ln<<<256, 256, 0, stream>>>(partial, KC, hacc, gamma2, beta2, (float*)d_out, 0);
}

// Round 8
// 178.505 us; speedup vs baseline: 4.6386x; 1.1426x over previous
//
#include <hip/hip_runtime.h>
#include <hip/hip_bf16.h>

// RGCN: N=4096, D=128, R=8, B=8, two layers + LN(+ReLU).
// R8: agg stages the per-ms B panel in LDS (2-phase r-split double buffer,
// reg-staged global->LDS with issue-early/write-late), killing the 1 GB/agg
// L2 re-read of xwfrag and the 64-bit address VALU. Wave = 32x64, 8 waves.

#define NN 4096
#define DD 128

typedef __attribute__((ext_vector_type(8))) short  s16x8;   // storage for 8 bf16
typedef __attribute__((ext_vector_type(8))) __bf16 bf16v8;  // MFMA operand type
typedef __attribute__((ext_vector_type(4))) float  f32x4;
typedef __attribute__((ext_vector_type(4))) int    i32x4;

__device__ inline short f2bf(float f) {            // f32 -> bf16 bits, RNE
  union { float f; unsigned u; } v; v.f = f;
  unsigned r = (v.u + 0x7FFFu + ((v.u >> 16) & 1u)) >> 16;
  return (short)r;
}

__device__ inline f32x4 mfma16(s16x8 a, s16x8 b, f32x4 c) {
  return __builtin_amdgcn_mfma_f32_16x16x32_bf16(
      __builtin_bit_cast(bf16v8, a), __builtin_bit_cast(bf16v8, b), c, 0, 0, 0);
}

// ---------------------------------------------------------------------------
// K0: pack adj (f32 -> bf16) and edge_type (i32 -> nibbles, 8/u32).
// etp words permuted within each 16-u32 group ((ms,l4) -> (l4,ms)) so agg
// lane l4 can load 4 consecutive ms-words as one i32x4.
// ---------------------------------------------------------------------------
__global__ void pack_kernel(const float* __restrict__ adj, const int* __restrict__ et,
                            short* __restrict__ adjb, unsigned* __restrict__ etp) {
  int g = blockIdx.x * 256 + threadIdx.x;     // linear u32 index, 0 .. 2M-1
  size_t base = (size_t)g * 8;
  f32x4 f0 = *(const f32x4*)(adj + base);
  f32x4 f1 = *(const f32x4*)(adj + base + 4);
  i32x4 e0 = *(const i32x4*)(et + base);
  i32x4 e1 = *(const i32x4*)(et + base + 4);
  short v[8];
#pragma unroll
  for (int e = 0; e < 4; ++e) v[e] = f2bf(f0[e]);
#pragma unroll
  for (int e = 0; e < 4; ++e) v[4 + e] = f2bf(f1[e]);
  unsigned pk = 0;
#pragma unroll
  for (int e = 0; e < 4; ++e) pk |= ((unsigned)e0[e] & 7u) << (4 * e);
#pragma unroll
  for (int e = 0; e < 4; ++e) pk |= ((unsigned)e1[e] & 7u) << (4 * (e + 4));
  *(s16x8*)(adjb + base) = *(s16x8*)v;
  int m8 = g & 511, row = g >> 9;
  int np = (m8 & ~15) | ((m8 & 3) << 2) | ((m8 >> 2) & 3);
  etp[(size_t)row * 512 + np] = pk;
}

// ---------------------------------------------------------------------------
// K1: w_r = sum_b weights[r,b]*bases[b] (r==8 -> W_self), pre-fragmented
// B-frags: [layer][r(9)][s(4)][t(8)][lane(64)][e(8)],
// elem = w[i = 32s+8*(l>>4)+e][o = 16t+(l&15)].
// ---------------------------------------------------------------------------
__global__ void prep_w(const float* __restrict__ b1, const float* __restrict__ w1,
                       const float* __restrict__ ws1,
                       const float* __restrict__ b2, const float* __restrict__ w2,
                       const float* __restrict__ ws2,
                       short* __restrict__ wfrag) {
  int tid = blockIdx.x * 256 + threadIdx.x;   // 0..36863 (2 layers x 18432)
  int layer = (tid >= 18432);
  int t0 = tid - layer * 18432;
  int lane = t0 & 63;
  int t = (t0 >> 6) & 7;
  int s = (t0 >> 9) & 3;
  int r = t0 >> 11;                            // 0..8
  const float* bases = layer ? b2 : b1;
  const float* wts   = layer ? w2 : w1;
  const float* wself = layer ? ws2 : ws1;
  int o  = t * 16 + (lane & 15);
  int i0 = s * 32 + 8 * (lane >> 4);
  short v[8];
#pragma unroll
  for (int e = 0; e < 8; ++e) {
    int i = i0 + e;
    float a;
    if (r < 8) {
      a = 0.f;
#pragma unroll
      for (int b = 0; b < 8; ++b)
        a += wts[r * 8 + b] * bases[((size_t)b * 128 + i) * 128 + o];
    } else {
      a = wself[(size_t)i * 128 + o];
    }
    v[e] = f2bf(a);
  }
  *(s16x8*)(wfrag + (size_t)tid * 8) = *(s16x8*)v;
}

// ---------------------------------------------------------------------------
// K2: xw_r = xin @ w_r for r=0..7 -> xwfrag (agg B-frag layout)
//     [r][mstep(128)][t(8)][lane(64)][e(8)]
//     r==8: hacc = xin @ W_self + bias (f32; base term for reduce)
// ---------------------------------------------------------------------------
__global__ void xw_gemm(const float* __restrict__ xin, const short* __restrict__ wfrag,
                        short* __restrict__ xwfrag, float* __restrict__ hacc,
                        const float* __restrict__ bias) {
  __shared__ short lds[4][32 * 128];
  int w = threadIdx.x >> 6, lane = threadIdx.x & 63;
  int widx = blockIdx.x * 4 + w;   // 0..1151
  int m = widx & 127;              // 32-row tile
  int r = widx >> 7;               // 0..8
  int l15 = lane & 15, l4 = lane >> 4;

  f32x4 acc[2][8] = {};

#pragma unroll
  for (int s = 0; s < 4; ++s) {
    s16x8 A[2];
#pragma unroll
    for (int nt = 0; nt < 2; ++nt) {
      const float* xp = xin + (size_t)(m * 32 + nt * 16 + l15) * 128 + s * 32 + 8 * l4;
      f32x4 f0 = *(const f32x4*)xp;
      f32x4 f1 = *(const f32x4*)(xp + 4);
      s16x8 av;
#pragma unroll
      for (int e = 0; e < 4; ++e) av[e] = f2bf(f0[e]);
#pragma unroll
      for (int e = 0; e < 4; ++e) av[4 + e] = f2bf(f1[e]);
      A[nt] = av;
    }
    const short* bp = wfrag + ((size_t)(r * 4 + s) * 8) * 512 + lane * 8;
#pragma unroll
    for (int t = 0; t < 8; ++t) {
      s16x8 B = *(const s16x8*)(bp + t * 512);
      acc[0][t] = mfma16(A[0], B, acc[0][t]);
      acc[1][t] = mfma16(A[1], B, acc[1][t]);
    }
  }

  if (r == 8) {
#pragma unroll
    for (int nt = 0; nt < 2; ++nt)
#pragma unroll
      for (int t = 0; t < 8; ++t)
#pragma unroll
        for (int j = 0; j < 4; ++j) {
          int row = m * 32 + nt * 16 + 4 * l4 + j;
          int col = t * 16 + l15;
          hacc[(size_t)row * 128 + col] = acc[nt][t][j] + bias[col];
        }
  } else {
#pragma unroll
    for (int nt = 0; nt < 2; ++nt)
#pragma unroll
      for (int t = 0; t < 8; ++t)
#pragma unroll
        for (int j = 0; j < 4; ++j)
          lds[w][(nt * 16 + 4 * l4 + j) * 128 + t * 16 + l15] = f2bf(acc[nt][t][j]);
    __syncthreads();
#pragma unroll
    for (int t = 0; t < 8; ++t) {
      short v[8];
#pragma unroll
      for (int e = 0; e < 8; ++e) v[e] = lds[w][(8 * l4 + e) * 128 + t * 16 + l15];
      *(s16x8*)(xwfrag + ((size_t)(r * 128 + m) * 8 + t) * 512 + lane * 8) = *(s16x8*)v;
    }
  }
}

// ---------------------------------------------------------------------------
// K3: partial[kc][rowblk] = sum_r masked-adj @ xw_r over this kc chunk.
// Grid dim3(KC,32), block = 512 threads = 8 waves (wr 0..3 x wc 0..1),
// wave tile = 32 rows x 64 cols, acc[2][4] = 32 AGPR.
// B panel staged in LDS: per ms-step 64 KB (8r x 8t x 1KB), split into two
// 32 KB phases (r0-3 / r4-7), double-buffered. Reg-staged (T14): 4 dwordx4
// global loads issued BEFORE phase compute, ds_write after, 1 barrier/phase.
// ---------------------------------------------------------------------------
template <bool PACKED>
__launch_bounds__(512, 4)
__global__ void agg_kernel(const float* __restrict__ adj, const int* __restrict__ et,
                           const short* __restrict__ adjb, const unsigned* __restrict__ etp,
                           const short* __restrict__ xwfrag, float* __restrict__ partial,
                           int msteps) {
  int tid = threadIdx.x;
  int w = tid >> 6, lane = tid & 63;
  int kc = blockIdx.x;
  int rowblk = blockIdx.y;
  int wr = w >> 1, wc = w & 1;
  int rowbase = rowblk * 128 + wr * 32;
  int l15 = lane & 15, l4 = lane >> 4;

  f32x4 acc[2][4] = {};

  if constexpr (PACKED) {
    __shared__ short bpanel[2][16384];          // 2 x 32 KB half-panels

    size_t r0 = (size_t)(rowbase + l15);
    size_t r1 = (size_t)(rowbase + 16 + l15);
    const short* ap0 = adjb + r0 * 4096 + kc * 256 + 8 * l4;
    const short* ap1 = adjb + r1 * 4096 + kc * 256 + 8 * l4;

    // nibble words: current 4-ms group (h), reloaded after ms==3 extraction
    i32x4 Vc0 = __builtin_nontemporal_load((const i32x4*)(etp + r0 * 512 + kc * 32 + l4 * 4));
    i32x4 Vc1 = __builtin_nontemporal_load((const i32x4*)(etp + r1 * 512 + kc * 32 + l4 * 4));

    // A prefetch ping-pong
    s16x8 A[2][2];
    A[0][0] = __builtin_nontemporal_load((const s16x8*)ap0);
    A[0][1] = __builtin_nontemporal_load((const s16x8*)ap1);

    // staging regs + helpers. thread tid stages chunk (i*512+tid):
    //   r_local = i, slice-linear offset = tid*8 shorts (t=tid>>6, lane=tid&63)
    s16x8 st[4];
    const short* xsrc = xwfrag + (size_t)tid * 8;
    auto stage_load = [&](int p, int gm2) {
#pragma unroll
      for (int i = 0; i < 4; ++i)
        st[i] = *(const s16x8*)(xsrc + (size_t)p * 2097152 + (size_t)gm2 * 4096 +
                                (size_t)i * 524288);
    };
    auto stage_write = [&](int bf) {
#pragma unroll
      for (int i = 0; i < 4; ++i)
        *(s16x8*)&bpanel[bf][(i * 512 + tid) * 8] = st[i];
    };

    // prologue: stage (p0, ms0)
    int gm0 = kc * 8;
    stage_load(0, gm0);
    stage_write(0);
    __syncthreads();

    int buf = 0;
#pragma unroll
    for (int ms = 0; ms < 8; ++ms) {
      int gm = gm0 + ms;
      int cur = ms & 1, nxt = cur ^ 1;
      if (ms < 7) {
        A[nxt][0] = __builtin_nontemporal_load((const s16x8*)(ap0 + (ms + 1) * 32));
        A[nxt][1] = __builtin_nontemporal_load((const s16x8*)(ap1 + (ms + 1) * 32));
      }
      unsigned pk0 = (unsigned)Vc0[ms & 3];
      unsigned pk1 = (unsigned)Vc1[ms & 3];
      s16x8 cd0, cd1;
#pragma unroll
      for (int e = 0; e < 8; ++e) {
        cd0[e] = (short)((pk0 >> (4 * e)) & 7u);
        cd1[e] = (short)((pk1 >> (4 * e)) & 7u);
      }
      if (ms == 3) {  // reload nibble words for ms 4..7 (used next ms)
        Vc0 = __builtin_nontemporal_load((const i32x4*)(etp + r0 * 512 + kc * 32 + 16 + l4 * 4));
        Vc1 = __builtin_nontemporal_load((const i32x4*)(etp + r1 * 512 + kc * 32 + 16 + l4 * 4));
      }
#pragma unroll
      for (int p = 0; p < 2; ++p) {
        bool last = (ms == 7) && (p == 1);
        if (!last)
          stage_load(p ^ 1, (p == 0) ? gm : gm + 1);   // issue-early (T14)
        // compute phase p (r = 4p .. 4p+3) from bpanel[buf]
#pragma unroll
        for (int rl = 0; rl < 4; ++rl) {
          const int r = p * 4 + rl;
          s16x8 b[4];
#pragma unroll
          for (int t = 0; t < 4; ++t)
            b[t] = *(const s16x8*)&bpanel[buf][(rl * 8 + wc * 4 + t) * 512 + lane * 8];
          s16x8 m0, m1;
#pragma unroll
          for (int e = 0; e < 8; ++e) {
            m0[e] = (cd0[e] == (short)r) ? A[cur][0][e] : (short)0;
            m1[e] = (cd1[e] == (short)r) ? A[cur][1][e] : (short)0;
          }
#pragma unroll
          for (int t = 0; t < 4; ++t) {
            acc[0][t] = mfma16(m0, b[t], acc[0][t]);
            acc[1][t] = mfma16(m1, b[t], acc[1][t]);
          }
        }
        if (!last)
          stage_write(buf ^ 1);                         // write-late (T14)
        __syncthreads();
        buf ^= 1;
      }
    }
  } else {
    for (int ms = 0; ms < msteps; ++ms) {
      int gm = kc * msteps + ms;
      s16x8 a[2]; s16x8 cd[2];
#pragma unroll
      for (int nt = 0; nt < 2; ++nt) {
        size_t rbase = (size_t)(rowbase + nt * 16 + l15) * 4096 + gm * 32 + 8 * l4;
        f32x4 f0 = __builtin_nontemporal_load((const f32x4*)(adj + rbase));
        f32x4 f1 = __builtin_nontemporal_load((const f32x4*)(adj + rbase + 4));
        i32x4 e0 = __builtin_nontemporal_load((const i32x4*)(et + rbase));
        i32x4 e1 = __builtin_nontemporal_load((const i32x4*)(et + rbase + 4));
        s16x8 av, c;
#pragma unroll
        for (int e = 0; e < 4; ++e) { av[e] = f2bf(f0[e]); c[e] = (short)e0[e]; }
#pragma unroll
        for (int e = 0; e < 4; ++e) { av[4 + e] = f2bf(f1[e]); c[4 + e] = (short)e1[e]; }
        a[nt] = av; cd[nt] = c;
      }
#pragma unroll
      for (int r = 0; r < 8; ++r) {
        const short* bp = xwfrag + ((size_t)(r * 128 + gm) * 8 + wc * 4) * 512 + lane * 8;
        s16x8 b[4];
#pragma unroll
        for (int t = 0; t < 4; ++t) b[t] = *(const s16x8*)(bp + t * 512);
        s16x8 m0, m1;
#pragma unroll
        for (int e = 0; e < 8; ++e) {
          m0[e] = (cd[0][e] == (short)r) ? a[0][e] : (short)0;
          m1[e] = (cd[1][e] == (short)r) ? a[1][e] : (short)0;
        }
#pragma unroll
        for (int t = 0; t < 4; ++t) {
          acc[0][t] = mfma16(m0, b[t], acc[0][t]);
          acc[1][t] = mfma16(m1, b[t], acc[1][t]);
        }
      }
    }
  }

  // epilogue: lane-contiguous f32x4 stores; wave store instr = 1KB contiguous
  float* tile = partial + ((size_t)kc * 32 + rowblk) * 16384;
#pragma unroll
  for (int nt = 0; nt < 2; ++nt)
#pragma unroll
    for (int t = 0; t < 4; ++t)
      __builtin_nontemporal_store(
          acc[nt][t], (f32x4*)(tile + (size_t)(((w * 2 + nt) * 4 + t) * 256 + lane * 4)));
}

// ---------------------------------------------------------------------------
// K4: out = LN( hacc + sum_kc partial[kc] ) (+ReLU).
// Tile layout inverse: value(row,col) at (((wr*2+wc)*2+nt)*4 + t)*256
//   + (l4*16+li)*4 + j, where row = wr*32+nt*16+4*l4+j, col = wc*64+t*16+li.
// One wave per 4-row quad; lane holds cols {lane, lane+64} x 4 rows.
// ---------------------------------------------------------------------------
__global__ void reduce_ln(const float* __restrict__ partial, int KC,
                          const float* __restrict__ hacc,
                          const float* __restrict__ gamma, const float* __restrict__ beta,
                          float* __restrict__ out, int relu) {
  int lane = threadIdx.x & 63;
  int g = blockIdx.x * 4 + (threadIdx.x >> 6);   // row-quad id, 0..1023
  int rowblk = g >> 5;
  int q = g & 31;                                 // quad within 128-row block
  int wr  = q >> 3;
  int nt  = (q >> 2) & 1;
  int l4g = q & 3;
  int rowbase = rowblk * 128 + q * 4;

  int c0 = lane, c1 = lane + 64;
  int t0 = lane >> 4, li = lane & 15;
  f32x4 v0, v1;
#pragma unroll
  for (int j = 0; j < 4; ++j) {
    v0[j] = hacc[(size_t)(rowbase + j) * 128 + c0];
    v1[j] = hacc[(size_t)(rowbase + j) * 128 + c1];
  }
  size_t off0 = (size_t)((((wr * 2 + 0) * 2 + nt) * 4 + t0) * 256) + (l4g * 16 + li) * 4;
  size_t off1 = (size_t)((((wr * 2 + 1) * 2 + nt) * 4 + t0) * 256) + (l4g * 16 + li) * 4;
  for (int kc = 0; kc < KC; ++kc) {
    const float* tile = partial + ((size_t)kc * 32 + rowblk) * 16384;
    f32x4 p0 = *(const f32x4*)(tile + off0);
    f32x4 p1 = *(const f32x4*)(tile + off1);
#pragma unroll
    for (int j = 0; j < 4; ++j) { v0[j] += p0[j]; v1[j] += p1[j]; }
  }

  f32x4 s, sq;
#pragma unroll
  for (int j = 0; j < 4; ++j) {
    s[j]  = v0[j] + v1[j];
    sq[j] = v0[j] * v0[j] + v1[j] * v1[j];
  }
#pragma unroll
  for (int off = 32; off; off >>= 1) {
#pragma unroll
    for (int j = 0; j < 4; ++j) {
      s[j]  += __shfl_xor(s[j],  off);
      sq[j] += __shfl_xor(sq[j], off);
    }
  }
  float g0 = gamma[c0], g1 = gamma[c1], b0 = beta[c0], b1 = beta[c1];
#pragma unroll
  for (int j = 0; j < 4; ++j) {
    float mu  = s[j] * (1.f / 128.f);
    float var = sq[j] * (1.f / 128.f) - mu * mu;
    float inv = rsqrtf(var + 1e-5f);
    float y0 = (v0[j] - mu) * inv * g0 + b0;
    float y1 = (v1[j] - mu) * inv * g1 + b1;
    if (relu) { y0 = fmaxf(y0, 0.f); y1 = fmaxf(y1, 0.f); }
    out[(size_t)(rowbase + j) * 128 + c0] = y0;
    out[(size_t)(rowbase + j) * 128 + c1] = y1;
  }
}

// ---------------------------------------------------------------------------
extern "C" void kernel_launch(void* const* d_in, const int* in_sizes, int n_in,
                              void* d_out, int out_size, void* d_ws, size_t ws_size,
                              hipStream_t stream) {
  const float* x      = (const float*)d_in[0];
  const float* adj    = (const float*)d_in[1];
  const int*   et     = (const int*)d_in[2];
  const float* bases1 = (const float*)d_in[3];
  const float* wts1   = (const float*)d_in[4];
  const float* wself1 = (const float*)d_in[5];
  const float* bself1 = (const float*)d_in[6];
  const float* bases2 = (const float*)d_in[7];
  const float* wts2   = (const float*)d_in[8];
  const float* wself2 = (const float*)d_in[9];
  const float* bself2 = (const float*)d_in[10];
  const float* gamma1 = (const float*)d_in[11];
  const float* beta1  = (const float*)d_in[12];
  const float* gamma2 = (const float*)d_in[13];
  const float* beta2  = (const float*)d_in[14];

  char* ws = (char*)d_ws;
  const size_t BASE = 589824ull + 8388608ull + 2097152ull + 2097152ull; // 13,172,736
  short* wfrag  = (short*)(ws);
  short* xwfrag = (short*)(ws + 589824);
  float* hacc   = (float*)(ws + 589824 + 8388608);
  float* h1     = (float*)(ws + 589824 + 8388608 + 2097152);

  // tier selection: partials (KC * 2 MiB) after BASE; packed buffers after that
  const size_t PACKSZ = 33554432ull + 8388608ull;   // adjb + etp
  int KC = 0; bool packed = false;
  if (ws_size >= BASE + 16ull * 2097152ull + PACKSZ) { KC = 16; packed = true; }
  if (!KC) {
    const int utiers[5] = {16, 8, 4, 2, 1};
    for (int i = 0; i < 5 && !KC; ++i)
      if (ws_size >= BASE + (size_t)utiers[i] * 2097152ull) KC = utiers[i];
    if (!KC) KC = 1;
  }
  float*    partial = (float*)(ws + BASE);
  short*    adjb    = (short*)(ws + BASE + (size_t)KC * 2097152ull);
  unsigned* etp     = (unsigned*)(ws + BASE + (size_t)KC * 2097152ull + 33554432ull);
  int msteps = 128 / KC;

  prep_w<<<144, 256, 0, stream>>>(bases1, wts1, wself1, bases2, wts2, wself2, wfrag);
  if (packed)
    pack_kernel<<<8192, 256, 0, stream>>>(adj, et, adjb, etp);

  dim3 agrid(KC, 32);

  // layer 1
  xw_gemm<<<288, 256, 0, stream>>>(x, wfrag, xwfrag, hacc, bself1);
  if (packed)
    agg_kernel<true ><<<agrid, 512, 0, stream>>>(adj, et, adjb, etp, xwfrag, partial, msteps);
  else
    agg_kernel<false><<<agrid, 512, 0, stream>>>(adj, et, adjb, etp, xwfrag, partial, msteps);
  reduce_ln<<<256, 256, 0, stream>>>(partial, KC, hacc, gamma1, beta1, h1, 1);

  // layer 2
  xw_gemm<<<288, 256, 0, stream>>>(h1, wfrag + 147456, xwfrag, hacc, bself2);
  if (packed)
    agg_kernel<true ><<<agrid, 512, 0, stream>>>(adj, et, adjb, etp, xwfrag, partial, msteps);
  else
    agg_kernel<false><<<agrid, 512, 0, stream>>>(adj, et, adjb, etp, xwfrag, partial, msteps);
  reduce_ln<<<256, 256, 0, stream>>>(partial, KC, hacc, gamma2, beta2, (float*)d_out, 0);
}

// Round 9
// 155.553 us; speedup vs baseline: 5.3231x; 1.1475x over previous
//
#include <hip/hip_runtime.h>
#include <hip/hip_bf16.h>

// RGCN: N=4096, D=128, R=8, B=8, two layers + LN(+ReLU).
// R9: branchless SWAR relation masking (one-hot bytes + v_perm + (x<<8)-x),
// wave = 16 rows x 128 cols (mask amortized over 8 o-tiles, no duplicate
// A-loads). LDS-staged B panel (R8), nt only on partial stores.

#define NN 4096
#define DD 128

typedef __attribute__((ext_vector_type(8))) short  s16x8;   // storage for 8 bf16
typedef __attribute__((ext_vector_type(8))) __bf16 bf16v8;  // MFMA operand type
typedef __attribute__((ext_vector_type(4))) float  f32x4;
typedef __attribute__((ext_vector_type(4))) int    i32x4;
typedef __attribute__((ext_vector_type(4))) unsigned u32x4;

__device__ inline short f2bf(float f) {            // f32 -> bf16 bits, RNE
  union { float f; unsigned u; } v; v.f = f;
  unsigned r = (v.u + 0x7FFFu + ((v.u >> 16) & 1u)) >> 16;
  return (short)r;
}

__device__ inline f32x4 mfma16(s16x8 a, s16x8 b, f32x4 c) {
  return __builtin_amdgcn_mfma_f32_16x16x32_bf16(
      __builtin_bit_cast(bf16v8, a), __builtin_bit_cast(bf16v8, b), c, 0, 0, 0);
}

// byte-pair -> halfword mask: q has bytes in {0,1}; pick bytes (i,i) (j,j),
// expand 0x01 -> 0xFF per byte, giving 0xFFFF per matching 16-bit lane.
__device__ inline unsigned pairmask(unsigned q, unsigned sel) {
#if __has_builtin(__builtin_amdgcn_perm)
  unsigned s = __builtin_amdgcn_perm(0u, q, sel);
#else
  unsigned b0 = (sel & 0xFF) ? ((q >> 8) & 1u) : (q & 1u);        // unused path
  unsigned s = 0;
#endif
  return (s << 8) - s;                         // 0x01 bytes -> 0xFF bytes
}

// ---------------------------------------------------------------------------
// K0: pack adj (f32 -> bf16) and edge_type (i32 -> one-hot bytes, 8/uint2).
// ---------------------------------------------------------------------------
__global__ void pack_kernel(const float* __restrict__ adj, const int* __restrict__ et,
                            short* __restrict__ adjb, unsigned* __restrict__ ohp) {
  int g = blockIdx.x * 256 + threadIdx.x;     // 8-elem group index, 0 .. 2M-1
  size_t base = (size_t)g * 8;
  f32x4 f0 = *(const f32x4*)(adj + base);
  f32x4 f1 = *(const f32x4*)(adj + base + 4);
  i32x4 e0 = *(const i32x4*)(et + base);
  i32x4 e1 = *(const i32x4*)(et + base + 4);
  short v[8];
#pragma unroll
  for (int e = 0; e < 4; ++e) v[e] = f2bf(f0[e]);
#pragma unroll
  for (int e = 0; e < 4; ++e) v[4 + e] = f2bf(f1[e]);
  unsigned oh0 = 0, oh1 = 0;
#pragma unroll
  for (int e = 0; e < 4; ++e) oh0 |= (1u << ((unsigned)e0[e] & 7u)) << (8 * e);
#pragma unroll
  for (int e = 0; e < 4; ++e) oh1 |= (1u << ((unsigned)e1[e] & 7u)) << (8 * e);
  *(s16x8*)(adjb + base) = *(s16x8*)v;
  ohp[2 * g]     = oh0;
  ohp[2 * g + 1] = oh1;
}

// ---------------------------------------------------------------------------
// K1: w_r = sum_b weights[r,b]*bases[b] (r==8 -> W_self), pre-fragmented
// B-frags: [layer][r(9)][s(4)][t(8)][lane(64)][e(8)],
// elem = w[i = 32s+8*(l>>4)+e][o = 16t+(l&15)].
// ---------------------------------------------------------------------------
__global__ void prep_w(const float* __restrict__ b1, const float* __restrict__ w1,
                       const float* __restrict__ ws1,
                       const float* __restrict__ b2, const float* __restrict__ w2,
                       const float* __restrict__ ws2,
                       short* __restrict__ wfrag) {
  int tid = blockIdx.x * 256 + threadIdx.x;   // 0..36863 (2 layers x 18432)
  int layer = (tid >= 18432);
  int t0 = tid - layer * 18432;
  int lane = t0 & 63;
  int t = (t0 >> 6) & 7;
  int s = (t0 >> 9) & 3;
  int r = t0 >> 11;                            // 0..8
  const float* bases = layer ? b2 : b1;
  const float* wts   = layer ? w2 : w1;
  const float* wself = layer ? ws2 : ws1;
  int o  = t * 16 + (lane & 15);
  int i0 = s * 32 + 8 * (lane >> 4);
  short v[8];
#pragma unroll
  for (int e = 0; e < 8; ++e) {
    int i = i0 + e;
    float a;
    if (r < 8) {
      a = 0.f;
#pragma unroll
      for (int b = 0; b < 8; ++b)
        a += wts[r * 8 + b] * bases[((size_t)b * 128 + i) * 128 + o];
    } else {
      a = wself[(size_t)i * 128 + o];
    }
    v[e] = f2bf(a);
  }
  *(s16x8*)(wfrag + (size_t)tid * 8) = *(s16x8*)v;
}

// ---------------------------------------------------------------------------
// K2: xw_r = xin @ w_r for r=0..7 -> xwfrag (agg B-frag layout)
//     [r][mstep(128)][t(8)][lane(64)][e(8)]
//     r==8: hacc = xin @ W_self + bias (f32; base term for reduce)
// ---------------------------------------------------------------------------
__global__ void xw_gemm(const float* __restrict__ xin, const short* __restrict__ wfrag,
                        short* __restrict__ xwfrag, float* __restrict__ hacc,
                        const float* __restrict__ bias) {
  __shared__ short lds[4][32 * 128];
  int w = threadIdx.x >> 6, lane = threadIdx.x & 63;
  int widx = blockIdx.x * 4 + w;   // 0..1151
  int m = widx & 127;              // 32-row tile
  int r = widx >> 7;               // 0..8
  int l15 = lane & 15, l4 = lane >> 4;

  f32x4 acc[2][8] = {};

#pragma unroll
  for (int s = 0; s < 4; ++s) {
    s16x8 A[2];
#pragma unroll
    for (int nt = 0; nt < 2; ++nt) {
      const float* xp = xin + (size_t)(m * 32 + nt * 16 + l15) * 128 + s * 32 + 8 * l4;
      f32x4 f0 = *(const f32x4*)xp;
      f32x4 f1 = *(const f32x4*)(xp + 4);
      s16x8 av;
#pragma unroll
      for (int e = 0; e < 4; ++e) av[e] = f2bf(f0[e]);
#pragma unroll
      for (int e = 0; e < 4; ++e) av[4 + e] = f2bf(f1[e]);
      A[nt] = av;
    }
    const short* bp = wfrag + ((size_t)(r * 4 + s) * 8) * 512 + lane * 8;
#pragma unroll
    for (int t = 0; t < 8; ++t) {
      s16x8 B = *(const s16x8*)(bp + t * 512);
      acc[0][t] = mfma16(A[0], B, acc[0][t]);
      acc[1][t] = mfma16(A[1], B, acc[1][t]);
    }
  }

  if (r == 8) {
#pragma unroll
    for (int nt = 0; nt < 2; ++nt)
#pragma unroll
      for (int t = 0; t < 8; ++t)
#pragma unroll
        for (int j = 0; j < 4; ++j) {
          int row = m * 32 + nt * 16 + 4 * l4 + j;
          int col = t * 16 + l15;
          hacc[(size_t)row * 128 + col] = acc[nt][t][j] + bias[col];
        }
  } else {
#pragma unroll
    for (int nt = 0; nt < 2; ++nt)
#pragma unroll
      for (int t = 0; t < 8; ++t)
#pragma unroll
        for (int j = 0; j < 4; ++j)
          lds[w][(nt * 16 + 4 * l4 + j) * 128 + t * 16 + l15] = f2bf(acc[nt][t][j]);
    __syncthreads();
#pragma unroll
    for (int t = 0; t < 8; ++t) {
      short v[8];
#pragma unroll
      for (int e = 0; e < 8; ++e) v[e] = lds[w][(8 * l4 + e) * 128 + t * 16 + l15];
      *(s16x8*)(xwfrag + ((size_t)(r * 128 + m) * 8 + t) * 512 + lane * 8) = *(s16x8*)v;
    }
  }
}

// ---------------------------------------------------------------------------
// K3: partial[kc][rowblk] = sum_r masked-adj @ xw_r over this kc chunk.
// Grid dim3(KC,32), block = 512 threads = 8 waves; wave = 16 rows x 128 cols
// (rows disjoint -> one masked A-frag feeds 8 MFMAs). acc[8] = 32 AGPR.
// Masking: one-hot bytes, (oh>>r)&0x01010101, v_perm pair-expand, (x<<8)-x,
// AND -- pure 32-bit VALU, no cmp/cndmask.
// B panel staged in LDS (2 phases x 32KB, double-buffered, issue-early).
// ---------------------------------------------------------------------------
template <bool PACKED>
__launch_bounds__(512, 4)
__global__ void agg_kernel(const float* __restrict__ adj, const int* __restrict__ et,
                           const short* __restrict__ adjb, const unsigned* __restrict__ ohp,
                           const short* __restrict__ xwfrag, float* __restrict__ partial,
                           int msteps) {
  int tid = threadIdx.x;
  int w = tid >> 6, lane = tid & 63;
  int kc = blockIdx.x;
  int rowblk = blockIdx.y;
  int l15 = lane & 15, l4 = lane >> 4;
  int row = rowblk * 128 + w * 16 + l15;

  f32x4 acc[8] = {};

  if constexpr (PACKED) {
    __shared__ short bpanel[2][16384];          // 2 x 32 KB half-panels

    // staging: thread tid stages r_local = i at LDS (i*512+tid)*8 shorts
    s16x8 st[4];
    const short* xsrc = xwfrag + (size_t)tid * 8;
    auto stage_load = [&](int p, int gm2) {
#pragma unroll
      for (int i = 0; i < 4; ++i)
        st[i] = *(const s16x8*)(xsrc + (size_t)(p * 4 + i) * 524288 + (size_t)gm2 * 4096);
    };
    auto stage_write = [&](int bf) {
#pragma unroll
      for (int i = 0; i < 4; ++i)
        *(s16x8*)&bpanel[bf][(i * 512 + tid) * 8] = st[i];
    };

    const int ngroups = msteps >> 3;
    for (int g = 0; g < ngroups; ++g) {
      int gmbase = kc * msteps + g * 8;
      const short*    ap = adjb + (size_t)row * 4096 + gmbase * 32 + 8 * l4;
      const unsigned* op = ohp + ((size_t)row * 512 + gmbase * 4 + l4) * 2;

      // A/oh prefetch ping-pong (plain loads; adjb/ohp are L2/L3-resident)
      s16x8 A[2];
      unsigned O[2][2];
      A[0] = *(const s16x8*)ap;
      O[0][0] = op[0]; O[0][1] = op[1];

      // prologue: stage phase0 of first ms
      stage_load(0, gmbase);
      stage_write(0);
      __syncthreads();

      int buf = 0;
#pragma unroll
      for (int ms = 0; ms < 8; ++ms) {
        int gm = gmbase + ms;
        int cur = ms & 1, nxt = cur ^ 1;
        if (ms < 7) {
          A[nxt] = *(const s16x8*)(ap + (ms + 1) * 32);
          O[nxt][0] = op[(ms + 1) * 8];
          O[nxt][1] = op[(ms + 1) * 8 + 1];
        }
        u32x4 av = __builtin_bit_cast(u32x4, A[cur]);
        unsigned o0 = O[cur][0], o1 = O[cur][1];

#pragma unroll
        for (int p = 0; p < 2; ++p) {
          bool last = (ms == 7) && (p == 1);
          if (!last)
            stage_load(p ^ 1, (p == 0) ? gm : gm + 1);   // issue-early (T14)
#pragma unroll
          for (int rl = 0; rl < 4; ++rl) {
            const int r = p * 4 + rl;
            // SWAR mask: bytes (oh>>r)&1 -> 0xFFFF halfword masks
            unsigned q0 = (o0 >> r) & 0x01010101u;
            unsigned q1 = (o1 >> r) & 0x01010101u;
            unsigned m0 = pairmask(q0, 0x01010000u);
            unsigned m1 = pairmask(q0, 0x03030202u);
            unsigned m2 = pairmask(q1, 0x01010000u);
            unsigned m3 = pairmask(q1, 0x03030202u);
            u32x4 mv;
            mv[0] = av[0] & m0; mv[1] = av[1] & m1;
            mv[2] = av[2] & m2; mv[3] = av[3] & m3;
            s16x8 mf = __builtin_bit_cast(s16x8, mv);
#pragma unroll
            for (int h = 0; h < 2; ++h) {
              s16x8 b[4];
#pragma unroll
              for (int t = 0; t < 4; ++t)
                b[t] = *(const s16x8*)&bpanel[buf][(rl * 8 + h * 4 + t) * 512 + lane * 8];
#pragma unroll
              for (int t = 0; t < 4; ++t)
                acc[h * 4 + t] = mfma16(mf, b[t], acc[h * 4 + t]);
            }
          }
          if (!last)
            stage_write(buf ^ 1);                         // write-late (T14)
          __syncthreads();
          buf ^= 1;
        }
      }
    }
  } else {
    for (int ms = 0; ms < msteps; ++ms) {
      int gm = kc * msteps + ms;
      size_t rbase = (size_t)row * 4096 + gm * 32 + 8 * l4;
      f32x4 f0 = *(const f32x4*)(adj + rbase);
      f32x4 f1 = *(const f32x4*)(adj + rbase + 4);
      i32x4 e0 = *(const i32x4*)(et + rbase);
      i32x4 e1 = *(const i32x4*)(et + rbase + 4);
      s16x8 a, cd;
#pragma unroll
      for (int e = 0; e < 4; ++e) { a[e] = f2bf(f0[e]); cd[e] = (short)e0[e]; }
#pragma unroll
      for (int e = 0; e < 4; ++e) { a[4 + e] = f2bf(f1[e]); cd[4 + e] = (short)e1[e]; }
#pragma unroll
      for (int r = 0; r < 8; ++r) {
        const short* bp = xwfrag + ((size_t)(r * 128 + gm) * 8) * 512 + lane * 8;
        s16x8 mf;
#pragma unroll
        for (int e = 0; e < 8; ++e) mf[e] = (cd[e] == (short)r) ? a[e] : (short)0;
#pragma unroll
        for (int t = 0; t < 8; ++t) {
          s16x8 b = *(const s16x8*)(bp + t * 512);
          acc[t] = mfma16(mf, b, acc[t]);
        }
      }
    }
  }

  // epilogue: lane-contiguous f32x4 stores (nt); wave region = 8KB contiguous
  float* tile = partial + ((size_t)kc * 32 + rowblk) * 16384;
#pragma unroll
  for (int t = 0; t < 8; ++t)
    __builtin_nontemporal_store(
        acc[t], (f32x4*)(tile + (size_t)((w * 8 + t) * 256 + lane * 4)));
}

// ---------------------------------------------------------------------------
// K4: out = LN( hacc + sum_kc partial[kc] ) (+ReLU).
// Tile inverse: value(row,col) at (w*8 + t)*256 + (l4*16+li)*4 + j,
//   row = w*16 + 4*l4 + j, col = t*16 + li.
// One wave per 4-row quad; lane holds cols {lane, lane+64} x 4 rows.
// ---------------------------------------------------------------------------
__global__ void reduce_ln(const float* __restrict__ partial, int KC,
                          const float* __restrict__ hacc,
                          const float* __restrict__ gamma, const float* __restrict__ beta,
                          float* __restrict__ out, int relu) {
  int lane = threadIdx.x & 63;
  int g = blockIdx.x * 4 + (threadIdx.x >> 6);   // row-quad id, 0..1023
  int rowblk = g >> 5;
  int q = g & 31;                                 // quad within 128-row block
  int wq  = q >> 2;
  int l4g = q & 3;
  int rowbase = rowblk * 128 + q * 4;

  int c0 = lane, c1 = lane + 64;
  int t0 = lane >> 4, li = lane & 15;
  f32x4 v0, v1;
#pragma unroll
  for (int j = 0; j < 4; ++j) {
    v0[j] = hacc[(size_t)(rowbase + j) * 128 + c0];
    v1[j] = hacc[(size_t)(rowbase + j) * 128 + c1];
  }
  size_t off0 = (size_t)((wq * 8 + t0) * 256) + (l4g * 16 + li) * 4;
  size_t off1 = (size_t)((wq * 8 + t0 + 4) * 256) + (l4g * 16 + li) * 4;
  for (int kc = 0; kc < KC; ++kc) {
    const float* tile = partial + ((size_t)kc * 32 + rowblk) * 16384;
    f32x4 p0 = *(const f32x4*)(tile + off0);
    f32x4 p1 = *(const f32x4*)(tile + off1);
#pragma unroll
    for (int j = 0; j < 4; ++j) { v0[j] += p0[j]; v1[j] += p1[j]; }
  }

  f32x4 s, sq;
#pragma unroll
  for (int j = 0; j < 4; ++j) {
    s[j]  = v0[j] + v1[j];
    sq[j] = v0[j] * v0[j] + v1[j] * v1[j];
  }
#pragma unroll
  for (int off = 32; off; off >>= 1) {
#pragma unroll
    for (int j = 0; j < 4; ++j) {
      s[j]  += __shfl_xor(s[j],  off);
      sq[j] += __shfl_xor(sq[j], off);
    }
  }
  float g0 = gamma[c0], g1 = gamma[c1], b0 = beta[c0], b1 = beta[c1];
#pragma unroll
  for (int j = 0; j < 4; ++j) {
    float mu  = s[j] * (1.f / 128.f);
    float var = sq[j] * (1.f / 128.f) - mu * mu;
    float inv = rsqrtf(var + 1e-5f);
    float y0 = (v0[j] - mu) * inv * g0 + b0;
    float y1 = (v1[j] - mu) * inv * g1 + b1;
    if (relu) { y0 = fmaxf(y0, 0.f); y1 = fmaxf(y1, 0.f); }
    out[(size_t)(rowbase + j) * 128 + c0] = y0;
    out[(size_t)(rowbase + j) * 128 + c1] = y1;
  }
}

// ---------------------------------------------------------------------------
extern "C" void kernel_launch(void* const* d_in, const int* in_sizes, int n_in,
                              void* d_out, int out_size, void* d_ws, size_t ws_size,
                              hipStream_t stream) {
  const float* x      = (const float*)d_in[0];
  const float* adj    = (const float*)d_in[1];
  const int*   et     = (const int*)d_in[2];
  const float* bases1 = (const float*)d_in[3];
  const float* wts1   = (const float*)d_in[4];
  const float* wself1 = (const float*)d_in[5];
  const float* bself1 = (const float*)d_in[6];
  const float* bases2 = (const float*)d_in[7];
  const float* wts2   = (const float*)d_in[8];
  const float* wself2 = (const float*)d_in[9];
  const float* bself2 = (const float*)d_in[10];
  const float* gamma1 = (const float*)d_in[11];
  const float* beta1  = (const float*)d_in[12];
  const float* gamma2 = (const float*)d_in[13];
  const float* beta2  = (const float*)d_in[14];

  char* ws = (char*)d_ws;
  const size_t BASE = 589824ull + 8388608ull + 2097152ull + 2097152ull; // 13,172,736
  short* wfrag  = (short*)(ws);
  short* xwfrag = (short*)(ws + 589824);
  float* hacc   = (float*)(ws + 589824 + 8388608);
  float* h1     = (float*)(ws + 589824 + 8388608 + 2097152);

  // tiers: partials (KC * 2 MiB) after BASE; packed buffers (adjb 32M + oh 16M)
  const size_t PACKSZ = 33554432ull + 16777216ull;
  int KC = 0; bool packed = false;
  {
    const int ptiers[3] = {16, 8, 2};
    for (int i = 0; i < 3 && !KC; ++i)
      if (ws_size >= BASE + (size_t)ptiers[i] * 2097152ull + PACKSZ) { KC = ptiers[i]; packed = true; }
    const int utiers[5] = {16, 8, 4, 2, 1};
    for (int i = 0; i < 5 && !KC; ++i)
      if (ws_size >= BASE + (size_t)utiers[i] * 2097152ull) KC = utiers[i];
    if (!KC) KC = 1;
  }
  float*    partial = (float*)(ws + BASE);
  short*    adjb    = (short*)(ws + BASE + (size_t)KC * 2097152ull);
  unsigned* ohp     = (unsigned*)(ws + BASE + (size_t)KC * 2097152ull + 33554432ull);
  int msteps = 128 / KC;

  prep_w<<<144, 256, 0, stream>>>(bases1, wts1, wself1, bases2, wts2, wself2, wfrag);
  if (packed)
    pack_kernel<<<8192, 256, 0, stream>>>(adj, et, adjb, ohp);

  dim3 agrid(KC, 32);

  // layer 1
  xw_gemm<<<288, 256, 0, stream>>>(x, wfrag, xwfrag, hacc, bself1);
  if (packed)
    agg_kernel<true ><<<agrid, 512, 0, stream>>>(adj, et, adjb, ohp, xwfrag, partial, msteps);
  else
    agg_kernel<false><<<agrid, 512, 0, stream>>>(adj, et, adjb, ohp, xwfrag, partial, msteps);
  reduce_ln<<<256, 256, 0, stream>>>(partial, KC, hacc, gamma1, beta1, h1, 1);

  // layer 2
  xw_gemm<<<288, 256, 0, stream>>>(h1, wfrag + 147456, xwfrag, hacc, bself2);
  if (packed)
    agg_kernel<true ><<<agrid, 512, 0, stream>>>(adj, et, adjb, ohp, xwfrag, partial, msteps);
  else
    agg_kernel<false><<<agrid, 512, 0, stream>>>(adj, et, adjb, ohp, xwfrag, partial, msteps);
  reduce_ln<<<256, 256, 0, stream>>>(partial, KC, hacc, gamma2, beta2, (float*)d_out, 0);
}

// Round 10
// 139.616 us; speedup vs baseline: 5.9307x; 1.1142x over previous
//
#include <hip/hip_runtime.h>
#include <hip/hip_bf16.h>

// RGCN: N=4096, D=128, R=8, B=8, two layers + LN(+ReLU).
// R10: aggregation on mfma_f32_32x32x16_bf16 (2x FLOP per B-fragment read:
// LDS ds_read count and MFMA instr count both halve). 8 waves x (32rows x
// 128cols), LDS-staged B panel (2x16KB dbuf), SWAR one-hot masking,
// bf16 partials. Pre-swizzled adj/one-hot fragment packing.

#define NN 4096
#define DD 128

typedef __attribute__((ext_vector_type(8)))  short    s16x8;
typedef __attribute__((ext_vector_type(4)))  short    s16x4;
typedef __attribute__((ext_vector_type(8)))  __bf16   bf16v8;
typedef __attribute__((ext_vector_type(4)))  float    f32x4;
typedef __attribute__((ext_vector_type(16))) float    f32x16;
typedef __attribute__((ext_vector_type(4)))  int      i32x4;
typedef __attribute__((ext_vector_type(4)))  unsigned u32x4;

__device__ inline short f2bf(float f) {            // f32 -> bf16 bits, RNE
  union { float f; unsigned u; } v; v.f = f;
  unsigned r = (v.u + 0x7FFFu + ((v.u >> 16) & 1u)) >> 16;
  return (short)r;
}
__device__ inline float bf2f(short h) {
  union { unsigned u; float f; } v; v.u = ((unsigned)(unsigned short)h) << 16;
  return v.f;
}

__device__ inline f32x4 mfma16(s16x8 a, s16x8 b, f32x4 c) {
  return __builtin_amdgcn_mfma_f32_16x16x32_bf16(
      __builtin_bit_cast(bf16v8, a), __builtin_bit_cast(bf16v8, b), c, 0, 0, 0);
}
__device__ inline f32x16 mfma32(s16x8 a, s16x8 b, f32x16 c) {
  return __builtin_amdgcn_mfma_f32_32x32x16_bf16(
      __builtin_bit_cast(bf16v8, a), __builtin_bit_cast(bf16v8, b), c, 0, 0, 0);
}

// byte-pair -> halfword mask: bytes of q in {0,1}; v_perm duplicates selected
// bytes, (x<<8)-x expands 0x01 -> 0xFFFF per 16-bit lane.
__device__ inline unsigned pairmask(unsigned q, unsigned sel) {
  unsigned s = __builtin_amdgcn_perm(0u, q, sel);
  return (s << 8) - s;
}

// ---------------------------------------------------------------------------
// K0p: pack adj/et into 32x32x16 A-fragment order + one-hot bytes.
// adjb32: [rt(128)][ks(256)][lane(64)][e(8)]  elem = adj[rt*32+(lane&31)]
//                                                    [ks*16+8*(lane>>5)+e]
// oh32:   same index, 2 dwords of one-hot bytes (elem e -> byte e of dword e/4)
// Block 256thr = 32 rows x 8 kgroups; writes are block-contiguous (4KB/2KB).
// ---------------------------------------------------------------------------
__global__ void pack32(const float* __restrict__ adj, const int* __restrict__ et,
                       short* __restrict__ adjb, unsigned* __restrict__ ohp) {
  int t = threadIdx.x;
  int kb = blockIdx.x, rb = blockIdx.y;
  int rl = t >> 3, kg = t & 7;
  int row = rb * 32 + rl;
  int k0  = kb * 64 + kg * 8;
  size_t src = (size_t)row * 4096 + k0;
  f32x4 f0 = *(const f32x4*)(adj + src);
  f32x4 f1 = *(const f32x4*)(adj + src + 4);
  i32x4 e0 = *(const i32x4*)(et + src);
  i32x4 e1 = *(const i32x4*)(et + src + 4);
  short v[8];
#pragma unroll
  for (int e = 0; e < 4; ++e) v[e] = f2bf(f0[e]);
#pragma unroll
  for (int e = 0; e < 4; ++e) v[4 + e] = f2bf(f1[e]);
  unsigned oh0 = 0, oh1 = 0;
#pragma unroll
  for (int e = 0; e < 4; ++e) oh0 |= (1u << ((unsigned)e0[e] & 7u)) << (8 * e);
#pragma unroll
  for (int e = 0; e < 4; ++e) oh1 |= (1u << ((unsigned)e1[e] & 7u)) << (8 * e);
  int ks   = kb * 4 + (kg >> 1);
  int lane = rl + 32 * (kg & 1);
  size_t didx = ((size_t)rb * 256 + ks) * 64 + lane;
  *(s16x8*)(adjb + didx * 8) = *(s16x8*)v;
  ohp[didx * 2]     = oh0;
  ohp[didx * 2 + 1] = oh1;
}

// K0f: fallback pack (row-major bf16 + permuted nibble words) — R9 layout.
__global__ void pack_fb(const float* __restrict__ adj, const int* __restrict__ et,
                        short* __restrict__ adjb, unsigned* __restrict__ etp) {
  int g = blockIdx.x * 256 + threadIdx.x;
  size_t base = (size_t)g * 8;
  f32x4 f0 = *(const f32x4*)(adj + base);
  f32x4 f1 = *(const f32x4*)(adj + base + 4);
  i32x4 e0 = *(const i32x4*)(et + base);
  i32x4 e1 = *(const i32x4*)(et + base + 4);
  short v[8];
#pragma unroll
  for (int e = 0; e < 4; ++e) v[e] = f2bf(f0[e]);
#pragma unroll
  for (int e = 0; e < 4; ++e) v[4 + e] = f2bf(f1[e]);
  unsigned oh0 = 0, oh1 = 0;
#pragma unroll
  for (int e = 0; e < 4; ++e) oh0 |= (1u << ((unsigned)e0[e] & 7u)) << (8 * e);
#pragma unroll
  for (int e = 0; e < 4; ++e) oh1 |= (1u << ((unsigned)e1[e] & 7u)) << (8 * e);
  *(s16x8*)(adjb + base) = *(s16x8*)v;
  etp[2 * g] = oh0; etp[2 * g + 1] = oh1;
}

// ---------------------------------------------------------------------------
// K1: w_r = sum_b weights[r,b]*bases[b] (r==8 -> W_self), 16x16 B-frag order
// (consumed only by xw_gemm): [layer][r(9)][s(4)][t(8)][lane][e(8)],
// elem = w[i = 32s+8*(l>>4)+e][o = 16t+(l&15)].
// ---------------------------------------------------------------------------
__global__ void prep_w(const float* __restrict__ b1, const float* __restrict__ w1,
                       const float* __restrict__ ws1,
                       const float* __restrict__ b2, const float* __restrict__ w2,
                       const float* __restrict__ ws2,
                       short* __restrict__ wfrag) {
  int tid = blockIdx.x * 256 + threadIdx.x;
  int layer = (tid >= 18432);
  int t0 = tid - layer * 18432;
  int lane = t0 & 63;
  int t = (t0 >> 6) & 7;
  int s = (t0 >> 9) & 3;
  int r = t0 >> 11;
  const float* bases = layer ? b2 : b1;
  const float* wts   = layer ? w2 : w1;
  const float* wself = layer ? ws2 : ws1;
  int o  = t * 16 + (lane & 15);
  int i0 = s * 32 + 8 * (lane >> 4);
  short v[8];
#pragma unroll
  for (int e = 0; e < 8; ++e) {
    int i = i0 + e;
    float a;
    if (r < 8) {
      a = 0.f;
#pragma unroll
      for (int b = 0; b < 8; ++b)
        a += wts[r * 8 + b] * bases[((size_t)b * 128 + i) * 128 + o];
    } else {
      a = wself[(size_t)i * 128 + o];
    }
    v[e] = f2bf(a);
  }
  *(s16x8*)(wfrag + (size_t)tid * 8) = *(s16x8*)v;
}

// ---------------------------------------------------------------------------
// K2: xw_r = xin @ w_r (16x16 MFMA; small kernel). LAYOUT=1 writes 32x32
// agg B-frags: [r][ks(256)][ct(4)][lane][e(8)], elem = xw[k][c],
//   k = ks*16 + 8*(l>>5)+e, c = ct*32 + (l&31).
// LAYOUT=0 writes R9 16x16 frags [r][gm(128)][t(8)][lane][e(8)].
// r==8: hacc = xin @ W_self + bias (row-major f32).
// ---------------------------------------------------------------------------
template <int LAYOUT>
__global__ void xw_gemm(const float* __restrict__ xin, const short* __restrict__ wfrag,
                        short* __restrict__ xwfrag, float* __restrict__ hacc,
                        const float* __restrict__ bias) {
  __shared__ short lds[4][32 * 128];
  int w = threadIdx.x >> 6, lane = threadIdx.x & 63;
  int widx = blockIdx.x * 4 + w;
  int m = widx & 127;
  int r = widx >> 7;
  int l15 = lane & 15, l4 = lane >> 4;

  f32x4 acc[2][8] = {};

#pragma unroll
  for (int s = 0; s < 4; ++s) {
    s16x8 A[2];
#pragma unroll
    for (int nt = 0; nt < 2; ++nt) {
      const float* xp = xin + (size_t)(m * 32 + nt * 16 + l15) * 128 + s * 32 + 8 * l4;
      f32x4 f0 = *(const f32x4*)xp;
      f32x4 f1 = *(const f32x4*)(xp + 4);
      s16x8 av;
#pragma unroll
      for (int e = 0; e < 4; ++e) av[e] = f2bf(f0[e]);
#pragma unroll
      for (int e = 0; e < 4; ++e) av[4 + e] = f2bf(f1[e]);
      A[nt] = av;
    }
    const short* bp = wfrag + ((size_t)(r * 4 + s) * 8) * 512 + lane * 8;
#pragma unroll
    for (int t = 0; t < 8; ++t) {
      s16x8 B = *(const s16x8*)(bp + t * 512);
      acc[0][t] = mfma16(A[0], B, acc[0][t]);
      acc[1][t] = mfma16(A[1], B, acc[1][t]);
    }
  }

  if (r == 8) {
#pragma unroll
    for (int nt = 0; nt < 2; ++nt)
#pragma unroll
      for (int t = 0; t < 8; ++t)
#pragma unroll
        for (int j = 0; j < 4; ++j) {
          int row = m * 32 + nt * 16 + 4 * l4 + j;
          int col = t * 16 + l15;
          hacc[(size_t)row * 128 + col] = acc[nt][t][j] + bias[col];
        }
  } else {
#pragma unroll
    for (int nt = 0; nt < 2; ++nt)
#pragma unroll
      for (int t = 0; t < 8; ++t)
#pragma unroll
        for (int j = 0; j < 4; ++j)
          lds[w][(nt * 16 + 4 * l4 + j) * 128 + t * 16 + l15] = f2bf(acc[nt][t][j]);
    __syncthreads();
    if (LAYOUT == 1) {
      int l31 = lane & 31, h = lane >> 5;
#pragma unroll
      for (int s = 0; s < 2; ++s)
#pragma unroll
        for (int ct = 0; ct < 4; ++ct) {
          short v[8];
#pragma unroll
          for (int e = 0; e < 8; ++e)
            v[e] = lds[w][(s * 16 + 8 * h + e) * 128 + ct * 32 + l31];
          *(s16x8*)(xwfrag + (((size_t)(r * 256 + m * 2 + s) * 4 + ct) * 64 + lane) * 8)
              = *(s16x8*)v;
        }
    } else {
#pragma unroll
      for (int t = 0; t < 8; ++t) {
        short v[8];
#pragma unroll
        for (int e = 0; e < 8; ++e) v[e] = lds[w][(8 * l4 + e) * 128 + t * 16 + l15];
        *(s16x8*)(xwfrag + ((size_t)(r * 128 + m) * 8 + t) * 512 + lane * 8) = *(s16x8*)v;
      }
    }
  }
}

// ---------------------------------------------------------------------------
// K3p: 32x32x16 aggregation. Grid (32 kc, 16 rowblk256), block 512 = 8 waves;
// wave = 32 rows x 128 cols, acc = 4 x f32x16. B panel LDS-staged:
// per ks 32KB split in two 16KB r-phases, double-buffered (issue-early /
// write-late). SWAR one-hot masking. bf16 partial tiles.
// Partial layout: [kc][rowblk][w(8)][ct(4)][rq(4)][lane][j(4)] bf16 (64KB).
// ---------------------------------------------------------------------------
__launch_bounds__(512, 4)
__global__ void agg32(const short* __restrict__ adjb, const unsigned* __restrict__ ohp,
                      const short* __restrict__ xw32, short* __restrict__ partial) {
  int tid = threadIdx.x;
  int w = tid >> 6, lane = tid & 63;
  int kc = blockIdx.x, rowblk = blockIdx.y;

  __shared__ short bpanel[2][8192];            // 2 x 16KB

  f32x16 acc[4] = {};

  int rt = rowblk * 8 + w;
  const short*    ap = adjb + ((size_t)rt * 256 + kc * 8) * 512 + lane * 8;
  const unsigned* op = ohp  + (((size_t)rt * 256 + kc * 8) * 64 + lane) * 2;

  s16x8 st[2];
  auto stage_load = [&](int p, int ks) {
#pragma unroll
    for (int i = 0; i < 2; ++i) {
      int idx = i * 512 + tid;
      int rl = idx >> 8, rem = idx & 255;
      st[i] = *(const s16x8*)(xw32 + ((size_t)(p * 4 + rl) * 256 + kc * 8 + ks) * 2048
                              + rem * 8);
    }
  };
  auto stage_write = [&](int bf) {
#pragma unroll
    for (int i = 0; i < 2; ++i) {
      int idx = i * 512 + tid;
      *(s16x8*)&bpanel[bf][idx * 8] = st[i];
    }
  };

  s16x8 A[2];
  unsigned O[2][2];
  A[0] = *(const s16x8*)ap;
  O[0][0] = op[0]; O[0][1] = op[1];

  stage_load(0, 0);
  stage_write(0);
  __syncthreads();

  int buf = 0;
#pragma unroll
  for (int ks = 0; ks < 8; ++ks) {
    int cur = ks & 1, nxt = cur ^ 1;
    if (ks < 7) {
      A[nxt] = *(const s16x8*)(ap + (ks + 1) * 512);
      O[nxt][0] = op[(ks + 1) * 128];
      O[nxt][1] = op[(ks + 1) * 128 + 1];
    }
    u32x4 av = __builtin_bit_cast(u32x4, A[cur]);
    unsigned o0 = O[cur][0], o1 = O[cur][1];

#pragma unroll
    for (int p = 0; p < 2; ++p) {
      bool last = (ks == 7) && (p == 1);
      if (!last)
        stage_load((p == 0) ? 1 : 0, (p == 0) ? ks : ks + 1);   // issue-early
#pragma unroll
      for (int rl = 0; rl < 4; ++rl) {
        const int r = p * 4 + rl;
        unsigned q0 = (o0 >> r) & 0x01010101u;
        unsigned q1 = (o1 >> r) & 0x01010101u;
        unsigned m0 = pairmask(q0, 0x01010000u);
        unsigned m1 = pairmask(q0, 0x03030202u);
        unsigned m2 = pairmask(q1, 0x01010000u);
        unsigned m3 = pairmask(q1, 0x03030202u);
        u32x4 mv;
        mv[0] = av[0] & m0; mv[1] = av[1] & m1;
        mv[2] = av[2] & m2; mv[3] = av[3] & m3;
        s16x8 mf = __builtin_bit_cast(s16x8, mv);
#pragma unroll
        for (int ct = 0; ct < 4; ++ct) {
          s16x8 b = *(const s16x8*)&bpanel[buf][((rl * 4 + ct) * 64 + lane) * 8];
          acc[ct] = mfma32(mf, b, acc[ct]);
        }
      }
      if (!last)
        stage_write(buf ^ 1);                                    // write-late
      __syncthreads();
      buf ^= 1;
    }
  }

  // epilogue: bf16 partials, 8B lane-contiguous stores
  short* tile = partial + ((size_t)(kc * 16 + rowblk)) * 32768;
#pragma unroll
  for (int ct = 0; ct < 4; ++ct)
#pragma unroll
    for (int rq = 0; rq < 4; ++rq) {
      short v[4];
#pragma unroll
      for (int j = 0; j < 4; ++j) v[j] = f2bf(acc[ct][rq * 4 + j]);
      __builtin_nontemporal_store(
          *(s16x4*)v, (s16x4*)(tile + ((size_t)((w * 4 + ct) * 4 + rq) * 64 + lane) * 4));
    }
}

// ---------------------------------------------------------------------------
// K4p: out = LN( hacc + sum_kc bf16-partial ) (+ReLU). One wave per 4-row
// quad. Inverse of agg32 store: value(row,col) short index in tile =
//   (((w*4+ct)*4+rq)*64 + (col&31)+32*bit2)*4 + (row&3),
//   w=(row>>5)&7, rq=(row>>3)&3, bit2=(row>>2)&1, ct=col>>5.
// ---------------------------------------------------------------------------
__global__ void reduce_ln32(const short* __restrict__ partial,
                            const float* __restrict__ hacc,
                            const float* __restrict__ gamma, const float* __restrict__ beta,
                            float* __restrict__ out, int relu) {
  int lane = threadIdx.x & 63;
  int g = blockIdx.x * 4 + (threadIdx.x >> 6);   // row-quad id, 0..1023
  int rowbase = g * 4;
  int rb   = rowbase >> 8;
  int w    = (rowbase >> 5) & 7;
  int rq   = (rowbase >> 3) & 3;
  int bit2 = (rowbase >> 2) & 1;
  int l31 = lane & 31;
  int ct0 = lane >> 5;
  int lsrc = l31 + 32 * bit2;
  int c0 = lane, c1 = lane + 64;

  f32x4 v0, v1;
#pragma unroll
  for (int j = 0; j < 4; ++j) {
    v0[j] = hacc[(size_t)(rowbase + j) * 128 + c0];
    v1[j] = hacc[(size_t)(rowbase + j) * 128 + c1];
  }
  size_t off0 = ((size_t)((w * 4 + ct0) * 4 + rq) * 64 + lsrc) * 4;
  size_t off1 = ((size_t)((w * 4 + ct0 + 2) * 4 + rq) * 64 + lsrc) * 4;
  for (int kc = 0; kc < 32; ++kc) {
    const short* tile = partial + ((size_t)(kc * 16 + rb)) * 32768;
    s16x4 p0 = *(const s16x4*)(tile + off0);
    s16x4 p1 = *(const s16x4*)(tile + off1);
#pragma unroll
    for (int j = 0; j < 4; ++j) { v0[j] += bf2f(p0[j]); v1[j] += bf2f(p1[j]); }
  }

  f32x4 s, sq;
#pragma unroll
  for (int j = 0; j < 4; ++j) {
    s[j]  = v0[j] + v1[j];
    sq[j] = v0[j] * v0[j] + v1[j] * v1[j];
  }
#pragma unroll
  for (int off = 32; off; off >>= 1) {
#pragma unroll
    for (int j = 0; j < 4; ++j) {
      s[j]  += __shfl_xor(s[j],  off);
      sq[j] += __shfl_xor(sq[j], off);
    }
  }
  float g0 = gamma[c0], g1 = gamma[c1], b0 = beta[c0], b1 = beta[c1];
#pragma unroll
  for (int j = 0; j < 4; ++j) {
    float mu  = s[j] * (1.f / 128.f);
    float var = sq[j] * (1.f / 128.f) - mu * mu;
    float inv = rsqrtf(var + 1e-5f);
    float y0 = (v0[j] - mu) * inv * g0 + b0;
    float y1 = (v1[j] - mu) * inv * g1 + b1;
    if (relu) { y0 = fmaxf(y0, 0.f); y1 = fmaxf(y1, 0.f); }
    out[(size_t)(rowbase + j) * 128 + c0] = y0;
    out[(size_t)(rowbase + j) * 128 + c1] = y1;
  }
}

// ---------------------------------------------------------------------------
// Fallback path (R9-proven): 16x16 agg from raw/packed-row-major inputs with
// f32 partials, and its reduce. Only used if ws_size is unexpectedly small.
// ---------------------------------------------------------------------------
__launch_bounds__(512, 4)
__global__ void agg_fb(const float* __restrict__ adj, const int* __restrict__ et,
                       const short* __restrict__ xwfrag, float* __restrict__ partial,
                       int msteps) {
  int tid = threadIdx.x;
  int w = tid >> 6, lane = tid & 63;
  int kc = blockIdx.x, rowblk = blockIdx.y;
  int l15 = lane & 15, l4 = lane >> 4;
  int row = rowblk * 128 + w * 16 + l15;

  f32x4 acc[8] = {};
  for (int ms = 0; ms < msteps; ++ms) {
    int gm = kc * msteps + ms;
    size_t rbase = (size_t)row * 4096 + gm * 32 + 8 * l4;
    f32x4 f0 = *(const f32x4*)(adj + rbase);
    f32x4 f1 = *(const f32x4*)(adj + rbase + 4);
    i32x4 e0 = *(const i32x4*)(et + rbase);
    i32x4 e1 = *(const i32x4*)(et + rbase + 4);
    s16x8 a, cd;
#pragma unroll
    for (int e = 0; e < 4; ++e) { a[e] = f2bf(f0[e]); cd[e] = (short)e0[e]; }
#pragma unroll
    for (int e = 0; e < 4; ++e) { a[4 + e] = f2bf(f1[e]); cd[4 + e] = (short)e1[e]; }
#pragma unroll
    for (int r = 0; r < 8; ++r) {
      const short* bp = xwfrag + ((size_t)(r * 128 + gm) * 8) * 512 + lane * 8;
      s16x8 mf;
#pragma unroll
      for (int e = 0; e < 8; ++e) mf[e] = (cd[e] == (short)r) ? a[e] : (short)0;
#pragma unroll
      for (int t = 0; t < 8; ++t) {
        s16x8 b = *(const s16x8*)(bp + t * 512);
        acc[t] = mfma16(mf, b, acc[t]);
      }
    }
  }
  float* tile = partial + ((size_t)kc * 32 + rowblk) * 16384;
#pragma unroll
  for (int t = 0; t < 8; ++t)
    __builtin_nontemporal_store(
        acc[t], (f32x4*)(tile + (size_t)((w * 8 + t) * 256 + lane * 4)));
}

__global__ void reduce_fb(const float* __restrict__ partial, int KC,
                          const float* __restrict__ hacc,
                          const float* __restrict__ gamma, const float* __restrict__ beta,
                          float* __restrict__ out, int relu) {
  int lane = threadIdx.x & 63;
  int g = blockIdx.x * 4 + (threadIdx.x >> 6);
  int rowblk = g >> 5;
  int q = g & 31;
  int wq  = q >> 2;
  int l4g = q & 3;
  int rowbase = rowblk * 128 + q * 4;
  int c0 = lane, c1 = lane + 64;
  int t0 = lane >> 4, li = lane & 15;
  f32x4 v0, v1;
#pragma unroll
  for (int j = 0; j < 4; ++j) {
    v0[j] = hacc[(size_t)(rowbase + j) * 128 + c0];
    v1[j] = hacc[(size_t)(rowbase + j) * 128 + c1];
  }
  size_t off0 = (size_t)((wq * 8 + t0) * 256) + (l4g * 16 + li) * 4;
  size_t off1 = (size_t)((wq * 8 + t0 + 4) * 256) + (l4g * 16 + li) * 4;
  for (int kc = 0; kc < KC; ++kc) {
    const float* tile = partial + ((size_t)kc * 32 + rowblk) * 16384;
    f32x4 p0 = *(const f32x4*)(tile + off0);
    f32x4 p1 = *(const f32x4*)(tile + off1);
#pragma unroll
    for (int j = 0; j < 4; ++j) { v0[j] += p0[j]; v1[j] += p1[j]; }
  }
  f32x4 s, sq;
#pragma unroll
  for (int j = 0; j < 4; ++j) {
    s[j]  = v0[j] + v1[j];
    sq[j] = v0[j] * v0[j] + v1[j] * v1[j];
  }
#pragma unroll
  for (int off = 32; off; off >>= 1) {
#pragma unroll
    for (int j = 0; j < 4; ++j) {
      s[j]  += __shfl_xor(s[j],  off);
      sq[j] += __shfl_xor(sq[j], off);
    }
  }
  float g0 = gamma[c0], g1 = gamma[c1], b0 = beta[c0], b1 = beta[c1];
#pragma unroll
  for (int j = 0; j < 4; ++j) {
    float mu  = s[j] * (1.f / 128.f);
    float var = sq[j] * (1.f / 128.f) - mu * mu;
    float inv = rsqrtf(var + 1e-5f);
    float y0 = (v0[j] - mu) * inv * g0 + b0;
    float y1 = (v1[j] - mu) * inv * g1 + b1;
    if (relu) { y0 = fmaxf(y0, 0.f); y1 = fmaxf(y1, 0.f); }
    out[(size_t)(rowbase + j) * 128 + c0] = y0;
    out[(size_t)(rowbase + j) * 128 + c1] = y1;
  }
}

// ---------------------------------------------------------------------------
extern "C" void kernel_launch(void* const* d_in, const int* in_sizes, int n_in,
                              void* d_out, int out_size, void* d_ws, size_t ws_size,
                              hipStream_t stream) {
  const float* x      = (const float*)d_in[0];
  const float* adj    = (const float*)d_in[1];
  const int*   et     = (const int*)d_in[2];
  const float* bases1 = (const float*)d_in[3];
  const float* wts1   = (const float*)d_in[4];
  const float* wself1 = (const float*)d_in[5];
  const float* bself1 = (const float*)d_in[6];
  const float* bases2 = (const float*)d_in[7];
  const float* wts2   = (const float*)d_in[8];
  const float* wself2 = (const float*)d_in[9];
  const float* bself2 = (const float*)d_in[10];
  const float* gamma1 = (const float*)d_in[11];
  const float* beta1  = (const float*)d_in[12];
  const float* gamma2 = (const float*)d_in[13];
  const float* beta2  = (const float*)d_in[14];

  char* ws = (char*)d_ws;
  const size_t BASE = 589824ull + 8388608ull + 2097152ull + 2097152ull; // 13,172,736
  short* wfrag  = (short*)(ws);
  short* xwfrag = (short*)(ws + 589824);
  float* hacc   = (float*)(ws + 589824 + 8388608);
  float* h1     = (float*)(ws + 589824 + 8388608 + 2097152);

  // packed tier: bf16 partials 32MB + adjb32 32MB + oh32 16MB after BASE
  const size_t P16 = 33554432ull, ADJSZ = 33554432ull, OHSZ = 16777216ull;
  bool packed = ws_size >= BASE + P16 + ADJSZ + OHSZ;   // 93.2 MB (proven OK)

  prep_w<<<144, 256, 0, stream>>>(bases1, wts1, wself1, bases2, wts2, wself2, wfrag);

  if (packed) {
    short*    partial16 = (short*)(ws + BASE);
    short*    adjb32    = (short*)(ws + BASE + P16);
    unsigned* oh32      = (unsigned*)(ws + BASE + P16 + ADJSZ);

    pack32<<<dim3(64, 128), 256, 0, stream>>>(adj, et, adjb32, oh32);

    dim3 agrid(32, 16);
    // layer 1
    xw_gemm<1><<<288, 256, 0, stream>>>(x, wfrag, xwfrag, hacc, bself1);
    agg32<<<agrid, 512, 0, stream>>>(adjb32, oh32, xwfrag, partial16);
    reduce_ln32<<<256, 256, 0, stream>>>(partial16, hacc, gamma1, beta1, h1, 1);
    // layer 2
    xw_gemm<1><<<288, 256, 0, stream>>>(h1, wfrag + 147456, xwfrag, hacc, bself2);
    agg32<<<agrid, 512, 0, stream>>>(adjb32, oh32, xwfrag, partial16);
    reduce_ln32<<<256, 256, 0, stream>>>(partial16, hacc, gamma2, beta2, (float*)d_out, 0);
  } else {
    // fallback: f32 partials, raw-input 16x16 agg
    int KC = 0;
    const int utiers[5] = {16, 8, 4, 2, 1};
    for (int i = 0; i < 5 && !KC; ++i)
      if (ws_size >= BASE + (size_t)utiers[i] * 2097152ull) KC = utiers[i];
    if (!KC) KC = 1;
    float* partialf = (float*)(ws + BASE);
    int msteps = 128 / KC;
    dim3 agrid(KC, 32);

    xw_gemm<0><<<288, 256, 0, stream>>>(x, wfrag, xwfrag, hacc, bself1);
    agg_fb<<<agrid, 512, 0, stream>>>(adj, et, xwfrag, partialf, msteps);
    reduce_fb<<<256, 256, 0, stream>>>(partialf, KC, hacc, gamma1, beta1, h1, 1);

    xw_gemm<0><<<288, 256, 0, stream>>>(h1, wfrag + 147456, xwfrag, hacc, bself2);
    agg_fb<<<agrid, 512, 0, stream>>>(adj, et, xwfrag, partialf, msteps);
    reduce_fb<<<256, 256, 0, stream>>>(partialf, KC, hacc, gamma2, beta2, (float*)d_out, 0);
  }
}